// Round 13
// baseline (204.569 us; speedup 1.0000x reference)
//
#include <hip/hip_runtime.h>
#include <hip/hip_bf16.h>
#include <hip/hip_fp8.h>

#define D_FEAT 64
#define H_SIZE 32
#define N_CLASSES 10
#define NPB 256          // nodes per bucket (bucket = dst >> 8)
#define MAXB 512
#define NCHUNK 256       // edge chunks for count/scatter passes
#define BT 1024
#define NT 256

using short8 = __attribute__((ext_vector_type(8))) short;
using f32x4v = __attribute__((ext_vector_type(4))) float;
using uint4v = __attribute__((ext_vector_type(4))) unsigned;

__device__ inline short f2bf(float f) {
    __hip_bfloat16 h = __float2bfloat16(f);
    return *reinterpret_cast<short*>(&h);
}

// fp8 byte -> float
#define F8(u, s) ({ __hip_fp8_e4m3 _f; _f.__x = (unsigned char)(((u) >> (s)) & 0xff); (float)_f; })

// accumulate 16 fp8 from a uint4v into a[0..15]
#define ACC16(p) do { \
    a[0]  += F8((p)[0], 0);  a[1]  += F8((p)[0], 8);  a[2]  += F8((p)[0], 16); a[3]  += F8((p)[0], 24); \
    a[4]  += F8((p)[1], 0);  a[5]  += F8((p)[1], 8);  a[6]  += F8((p)[1], 16); a[7]  += F8((p)[1], 24); \
    a[8]  += F8((p)[2], 0);  a[9]  += F8((p)[2], 8);  a[10] += F8((p)[2], 16); a[11] += F8((p)[2], 24); \
    a[12] += F8((p)[3], 0);  a[13] += F8((p)[3], 8);  a[14] += F8((p)[3], 16); a[15] += F8((p)[3], 24); } while (0)

// accumulate 8 bf16 from a uint4v into a[0..7]
#define ACC8(p) do { \
    a[0] += __uint_as_float((p)[0] << 16); a[1] += __uint_as_float((p)[0] & 0xFFFF0000u); \
    a[2] += __uint_as_float((p)[1] << 16); a[3] += __uint_as_float((p)[1] & 0xFFFF0000u); \
    a[4] += __uint_as_float((p)[2] << 16); a[5] += __uint_as_float((p)[2] & 0xFFFF0000u); \
    a[6] += __uint_as_float((p)[3] << 16); a[7] += __uint_as_float((p)[3] & 0xFFFF0000u); } while (0)

// ---------- dense1 via MFMA: O = x @ [W1_rel^T | W1_root^T] ---------------

__global__ __launch_bounds__(NT) void dense1_mfma(
    const float* __restrict__ x, const float* __restrict__ W1_rel,
    const float* __restrict__ b1, const float* __restrict__ W1_root,
    unsigned* __restrict__ xr8, float* __restrict__ xroot, int n_nodes) {
    __shared__ unsigned short sW[64 * 72];   // [outcol n][k] bf16, pad 72
    __shared__ float sOut[64 * 65];          // [node][outcol] f32, pad 65
    __shared__ float sb[H_SIZE];
    int tid = threadIdx.x;
    for (int i = tid; i < 64 * 64; i += NT) {
        int n = i >> 6, k = i & 63;
        float w = (n < 32) ? W1_rel[n * 64 + k] : W1_root[(n - 32) * 64 + k];
        sW[n * 72 + k] = (unsigned short)f2bf(w);
    }
    if (tid < H_SIZE) sb[tid] = b1[tid];
    __syncthreads();

    int lane = tid & 63, wave = tid >> 6;
    int r16 = lane & 15, h = lane >> 4;

    short8 bf[4][2];
#pragma unroll
    for (int t = 0; t < 4; ++t)
#pragma unroll
        for (int s = 0; s < 2; ++s) {
            const unsigned short* p = &sW[(t * 16 + r16) * 72 + s * 32 + h * 8];
            bf[t][s] = *reinterpret_cast<const short8*>(p);
        }

    int nbase = blockIdx.x * 64 + wave * 16;
    int row = nbase + r16;
    int rowc = min(row, n_nodes - 1);

    short8 af[2];
#pragma unroll
    for (int s = 0; s < 2; ++s) {
        const float* px = x + (size_t)rowc * D_FEAT + s * 32 + h * 8;
        float4 lo = *reinterpret_cast<const float4*>(px);
        float4 hi = *reinterpret_cast<const float4*>(px + 4);
        short8 a;
        a[0] = f2bf(lo.x); a[1] = f2bf(lo.y); a[2] = f2bf(lo.z); a[3] = f2bf(lo.w);
        a[4] = f2bf(hi.x); a[5] = f2bf(hi.y); a[6] = f2bf(hi.z); a[7] = f2bf(hi.w);
        af[s] = a;
    }

    f32x4v acc[4] = {{0.f,0.f,0.f,0.f},{0.f,0.f,0.f,0.f},
                     {0.f,0.f,0.f,0.f},{0.f,0.f,0.f,0.f}};
#pragma unroll
    for (int t = 0; t < 4; ++t) {
        acc[t] = __builtin_amdgcn_mfma_f32_16x16x32_bf16(af[0], bf[t][0], acc[t], 0, 0, 0);
        acc[t] = __builtin_amdgcn_mfma_f32_16x16x32_bf16(af[1], bf[t][1], acc[t], 0, 0, 0);
    }
#pragma unroll
    for (int t = 0; t < 4; ++t)
#pragma unroll
        for (int r = 0; r < 4; ++r)
            sOut[(wave * 16 + h * 4 + r) * 65 + t * 16 + r16] = acc[t][r];
    __syncthreads();

    int nl = lane;
    int g = blockIdx.x * 64 + nl;
    if (g < n_nodes) {
        if (wave < 2) {
            unsigned w4[4];
#pragma unroll
            for (int q = 0; q < 4; ++q) {
                unsigned wd = 0;
#pragma unroll
                for (int b = 0; b < 4; ++b) {
                    float v = sOut[nl * 65 + wave * 16 + q * 4 + b];
                    __hip_fp8_e4m3 f8(v);
                    wd |= ((unsigned)f8.__x) << (8 * b);
                }
                w4[q] = wd;
            }
            *reinterpret_cast<uint4*>(&xr8[(size_t)g * 8 + wave * 4]) =
                make_uint4(w4[0], w4[1], w4[2], w4[3]);
        } else {
            int co = (wave - 2) * 16;
#pragma unroll
            for (int q = 0; q < 4; ++q) {
                float4 v;
                v.x = sOut[nl * 65 + 32 + co + q * 4 + 0] + sb[co + q * 4 + 0];
                v.y = sOut[nl * 65 + 32 + co + q * 4 + 1] + sb[co + q * 4 + 1];
                v.z = sOut[nl * 65 + 32 + co + q * 4 + 2] + sb[co + q * 4 + 2];
                v.w = sOut[nl * 65 + 32 + co + q * 4 + 3] + sb[co + q * 4 + 3];
                *reinterpret_cast<float4*>(&xroot[(size_t)g * 32 + co + q * 4]) = v;
            }
        }
    }
}

// ---------- bucket count -> hierarchical scan -> scatter -------------------

__global__ __launch_bounds__(BT) void bucket_count(
    const int* __restrict__ dst, int* __restrict__ counts,
    int n_edges, int nbuckets, int ept) {
    __shared__ int hist[MAXB];
    for (int i = threadIdx.x; i < nbuckets; i += BT) hist[i] = 0;
    __syncthreads();
    int beg = blockIdx.x * ept;
    int end = min(beg + ept, n_edges);
    for (int e = beg + threadIdx.x; e < end; e += BT)
        atomicAdd(&hist[__builtin_nontemporal_load(&dst[e]) >> 8], 1);
    __syncthreads();
    for (int b = threadIdx.x; b < nbuckets; b += BT)
        counts[b * NCHUNK + blockIdx.x] = hist[b];
}

__global__ __launch_bounds__(NPB) void bucket_totals(
    const int* __restrict__ counts, int* __restrict__ totals) {
    int b = blockIdx.x, tid = threadIdx.x;
    int v = counts[b * NCHUNK + tid];
#pragma unroll
    for (int o = 32; o > 0; o >>= 1) v += __shfl_down(v, o, 64);
    __shared__ int part[NPB / 64];
    if ((tid & 63) == 0) part[tid >> 6] = v;
    __syncthreads();
    if (tid == 0) {
        int s = 0;
#pragma unroll
        for (int w = 0; w < NPB / 64; ++w) s += part[w];
        totals[b] = s;
    }
}

__global__ __launch_bounds__(MAXB) void scan_small(
    const int* __restrict__ totals, int* __restrict__ bbase, int nbuckets) {
    __shared__ int lds[MAXB];
    int tid = threadIdx.x;
    int v = (tid < nbuckets) ? totals[tid] : 0;
    lds[tid] = v;
    __syncthreads();
    for (int off = 1; off < MAXB; off <<= 1) {
        int t = (tid >= off) ? lds[tid - off] : 0;
        __syncthreads();
        lds[tid] += t;
        __syncthreads();
    }
    if (tid < nbuckets) bbase[tid] = lds[tid] - v;
}

__global__ __launch_bounds__(NPB) void scan_within(
    int* __restrict__ counts, const int* __restrict__ bbase) {
    __shared__ int lds[NPB];
    int b = blockIdx.x, tid = threadIdx.x;
    int v = counts[b * NCHUNK + tid];
    lds[tid] = v;
    __syncthreads();
    for (int off = 1; off < NPB; off <<= 1) {
        int t = (tid >= off) ? lds[tid - off] : 0;
        __syncthreads();
        lds[tid] += t;
        __syncthreads();
    }
    counts[b * NCHUNK + tid] = bbase[b] + lds[tid] - v;
}

__global__ __launch_bounds__(BT) void bucket_scatter(
    const int* __restrict__ src, const int* __restrict__ dst,
    const int* __restrict__ base, unsigned* __restrict__ packed,
    int n_edges, int nbuckets, int ept) {
    __shared__ int cur[MAXB];
    for (int b = threadIdx.x; b < nbuckets; b += BT)
        cur[b] = base[b * NCHUNK + blockIdx.x];
    __syncthreads();
    int beg = blockIdx.x * ept;
    int end = min(beg + ept, n_edges);
    for (int e = beg + threadIdx.x; e < end; e += BT) {
        int s = __builtin_nontemporal_load(&src[e]);
        int d = __builtin_nontemporal_load(&dst[e]);
        int slot = atomicAdd(&cur[d >> 8], 1);
        packed[slot] = (unsigned)s | ((unsigned)(d & 255) << 24);
    }
}

// ---------- per-bucket counting sort -> global CSR -------------------------

__global__ __launch_bounds__(NPB) void csr_build(
    const unsigned* __restrict__ packed, const int* __restrict__ base,
    int* __restrict__ rowptr, int* __restrict__ csr,
    int n_nodes, int nbuckets, int n_edges) {
    __shared__ int cnt[NPB];
    __shared__ int cur[NPB];
    int b = blockIdx.x, tid = threadIdx.x;
    int pBeg = base[b * NCHUNK];
    int pEnd = (b + 1 < nbuckets) ? base[(b + 1) * NCHUNK] : n_edges;
    cnt[tid] = 0;
    __syncthreads();
    for (int i = pBeg + tid; i < pEnd; i += NPB)
        atomicAdd(&cnt[packed[i] >> 24], 1);
    __syncthreads();
    int v = cnt[tid];
    cur[tid] = v;
    __syncthreads();
    for (int off = 1; off < NPB; off <<= 1) {
        int t = (tid >= off) ? cur[tid - off] : 0;
        __syncthreads();
        cur[tid] += t;
        __syncthreads();
    }
    int gbase = pBeg + cur[tid] - v;
    int n = (b << 8) + tid;
    if (n < n_nodes) rowptr[n] = gbase;
    if (b == nbuckets - 1 && tid == 0) rowptr[n_nodes] = n_edges;
    cur[tid] = gbase;
    __syncthreads();
    for (int i = pBeg + tid; i < pEnd; i += NPB) {
        unsigned p = packed[i];
        int slot = atomicAdd(&cur[p >> 24], 1);
        csr[slot] = (int)(p & 0xFFFFFF);
    }
}

// ---------- gather1 (+fused dense2): 2 lanes/node, uint4 (16 fp8) loads ----
// streams (csr, xroot) and outputs (h2, hroot) use nt hints; xr8 table cached

__global__ __launch_bounds__(NT) void gather1_kernel(
    const uint4v* __restrict__ xr8v,       // 2 uint4 per node row (32 fp8)
    const float* __restrict__ xroot,
    const int* __restrict__ rowptr, const int* __restrict__ csr,
    const float* __restrict__ W2_rel, const float* __restrict__ b2,
    const float* __restrict__ W2_root,
    __hip_bfloat16* __restrict__ h2, float* __restrict__ hroot, int n_nodes) {
    __shared__ float sWrelT[H_SIZE * 17];  // [j][c] stride 17
    __shared__ float sWrootT[H_SIZE * 17];
    __shared__ float sb[16];
    __shared__ float sh[128][33];          // 128 nodes/block
    int tid = threadIdx.x;
    for (int i = tid; i < H_SIZE * 17; i += NT) { sWrelT[i] = 0.f; sWrootT[i] = 0.f; }
    __syncthreads();
    for (int i = tid; i < N_CLASSES * H_SIZE; i += NT) {
        int c = i >> 5, j = i & 31;
        sWrelT[j * 17 + c] = W2_rel[i];
        sWrootT[j * 17 + c] = W2_root[i];
    }
    if (tid < 16) sb[tid] = (tid < N_CLASSES) ? b2[tid] : 0.f;

    int t = blockIdx.x * NT + tid;
    int n = t >> 1, c1 = t & 1;            // 2 lanes/node; c1 = 16-feat half
    float a[16] = {0.f,0.f,0.f,0.f,0.f,0.f,0.f,0.f,
                   0.f,0.f,0.f,0.f,0.f,0.f,0.f,0.f};
    if (n < n_nodes) {
        int beg = rowptr[n], end = rowptr[n + 1];
        int i = beg;
        for (; i + 4 <= end; i += 4) {     // 4 edges per iter, 4 loads in flight
            int e0 = __builtin_nontemporal_load(&csr[i + c1]);
            int e1 = __builtin_nontemporal_load(&csr[i + 2 + c1]);
            uint4v p0 = xr8v[(size_t)__shfl(e0, 0, 2) * 2 + c1];
            uint4v p1 = xr8v[(size_t)__shfl(e0, 1, 2) * 2 + c1];
            uint4v p2 = xr8v[(size_t)__shfl(e1, 0, 2) * 2 + c1];
            uint4v p3 = xr8v[(size_t)__shfl(e1, 1, 2) * 2 + c1];
            ACC16(p0); ACC16(p1); ACC16(p2); ACC16(p3);
        }
        if (i + 2 <= end) {
            int e0 = __builtin_nontemporal_load(&csr[i + c1]);
            uint4v p0 = xr8v[(size_t)__shfl(e0, 0, 2) * 2 + c1];
            uint4v p1 = xr8v[(size_t)__shfl(e0, 1, 2) * 2 + c1];
            ACC16(p0); ACC16(p1);
            i += 2;
        }
        if (i < end) {                     // single leftover edge (broadcast)
            int e = __builtin_nontemporal_load(&csr[i]);
            uint4v p = xr8v[(size_t)e * 2 + c1];
            ACC16(p);
        }
        // root + bias + relu for feats c1*16 .. c1*16+15
        const f32x4v* xr4 = reinterpret_cast<const f32x4v*>(
            xroot + (size_t)n * 32 + c1 * 16);
#pragma unroll
        for (int q = 0; q < 4; ++q) {
            f32x4v v = __builtin_nontemporal_load(&xr4[q]);
            a[q * 4 + 0] = fmaxf(a[q * 4 + 0] + v[0], 0.f);
            a[q * 4 + 1] = fmaxf(a[q * 4 + 1] + v[1], 0.f);
            a[q * 4 + 2] = fmaxf(a[q * 4 + 2] + v[2], 0.f);
            a[q * 4 + 3] = fmaxf(a[q * 4 + 3] + v[3], 0.f);
        }
    }
    int nl = tid >> 1;
#pragma unroll
    for (int j = 0; j < 16; ++j) sh[nl][c1 * 16 + j] = a[j];
    __syncthreads();

    // fused dense2: 128 nodes x 16 cols = 2048 items, 8 passes
#pragma unroll
    for (int pass = 0; pass < 8; ++pass) {
        int idx = pass * NT + tid;
        int nl2 = idx >> 4, c = idx & 15;
        int n2 = blockIdx.x * 128 + nl2;
        if (n2 < n_nodes) {
            float ar = 0.f, ao = 0.f;
#pragma unroll
            for (int j = 0; j < H_SIZE; ++j) {
                float hv = sh[nl2][j];
                ar += hv * sWrelT[j * 17 + c];
                ao += hv * sWrootT[j * 17 + c];
            }
            // h2 is the next gather table: cached store; hroot is stream: nt
            h2[(size_t)n2 * 16 + c] = __float2bfloat16(ar);
            __builtin_nontemporal_store(ao + sb[c], &hroot[(size_t)n2 * 16 + c]);
        }
    }
}

// ---------- gather2 + loss: 2 lanes/node, uint4 (8 bf16) loads -------------

__global__ __launch_bounds__(NT) void gather2_loss_kernel(
    const uint4v* __restrict__ h2v,        // 2 uint4 per node row (16 bf16)
    const float* __restrict__ hroot,
    const int* __restrict__ rowptr, const int* __restrict__ csr,
    const int* __restrict__ y, float* __restrict__ loss,
    int n_nodes, float invN) {
    int t = blockIdx.x * NT + threadIdx.x;
    int n = t >> 1, c1 = t & 1;            // c1 = 8-class half
    int lane = threadIdx.x & 63;
    bool active = (n < n_nodes);

    float a[8] = {0.f,0.f,0.f,0.f,0.f,0.f,0.f,0.f};
    int yv = 0;
    if (active) {
        int beg = rowptr[n], end = rowptr[n + 1];
        int i = beg;
        for (; i + 4 <= end; i += 4) {
            int e0 = __builtin_nontemporal_load(&csr[i + c1]);
            int e1 = __builtin_nontemporal_load(&csr[i + 2 + c1]);
            uint4v p0 = h2v[(size_t)__shfl(e0, 0, 2) * 2 + c1];
            uint4v p1 = h2v[(size_t)__shfl(e0, 1, 2) * 2 + c1];
            uint4v p2 = h2v[(size_t)__shfl(e1, 0, 2) * 2 + c1];
            uint4v p3 = h2v[(size_t)__shfl(e1, 1, 2) * 2 + c1];
            ACC8(p0); ACC8(p1); ACC8(p2); ACC8(p3);
        }
        if (i + 2 <= end) {
            int e0 = __builtin_nontemporal_load(&csr[i + c1]);
            uint4v p0 = h2v[(size_t)__shfl(e0, 0, 2) * 2 + c1];
            uint4v p1 = h2v[(size_t)__shfl(e0, 1, 2) * 2 + c1];
            ACC8(p0); ACC8(p1);
            i += 2;
        }
        if (i < end) {
            int e = __builtin_nontemporal_load(&csr[i]);
            uint4v p = h2v[(size_t)e * 2 + c1];
            ACC8(p);
        }
        const f32x4v* hr4 = reinterpret_cast<const f32x4v*>(
            hroot + (size_t)n * 16 + c1 * 8);
        f32x4v h0 = __builtin_nontemporal_load(&hr4[0]);
        f32x4v h1 = __builtin_nontemporal_load(&hr4[1]);
        a[0] += h0[0]; a[1] += h0[1]; a[2] += h0[2]; a[3] += h0[3];
        a[4] += h1[0]; a[5] += h1[1]; a[6] += h1[2]; a[7] += h1[3];
        yv = __builtin_nontemporal_load(&y[n]);
    }
    // log-softmax: lane c1=0 holds classes 0..7, lane c1=1 holds 8..15 (8,9 valid)
    bool full = active && (c1 == 0);
    float m = -INFINITY;
#pragma unroll
    for (int j = 0; j < 8; ++j) {
        bool v = (j < 2) ? active : full;
        m = fmaxf(m, v ? a[j] : -INFINITY);
    }
    m = fmaxf(m, __shfl_xor(m, 1, 64));
    float es = 0.f;
#pragma unroll
    for (int j = 0; j < 8; ++j) {
        bool v = (j < 2) ? active : full;
        es += v ? expf(a[j] - m) : 0.f;
    }
    es += __shfl_xor(es, 1, 64);
    int yl = yv & 7;
    float lyc = 0.f;
#pragma unroll
    for (int j = 0; j < 8; ++j) lyc = (j == yl) ? a[j] : lyc;
    float ly = __shfl(lyc, (lane & ~1) + (yv >> 3), 64);
    float contrib = (active && c1 == 0) ? (m + logf(es) - ly) * invN : 0.f;

#pragma unroll
    for (int o = 32; o > 0; o >>= 1) contrib += __shfl_down(contrib, o, 64);
    __shared__ float part[NT / 64];
    if (lane == 0) part[threadIdx.x >> 6] = contrib;
    __syncthreads();
    if (threadIdx.x == 0) {
        float v = 0.f;
#pragma unroll
        for (int w = 0; w < NT / 64; ++w) v += part[w];
        atomicAdd(loss, v);
    }
}

// ---------------------------------------------------------------------------

extern "C" void kernel_launch(void* const* d_in, const int* in_sizes, int n_in,
                              void* d_out, int out_size, void* d_ws, size_t ws_size,
                              hipStream_t stream) {
    const float* x       = (const float*)d_in[0];
    const int*   ei      = (const int*)d_in[1];
    const int*   y       = (const int*)d_in[2];
    const float* W1_rel  = (const float*)d_in[3];
    const float* b1_rel  = (const float*)d_in[4];
    const float* W1_root = (const float*)d_in[5];
    const float* W2_rel  = (const float*)d_in[6];
    const float* b2_rel  = (const float*)d_in[7];
    const float* W2_root = (const float*)d_in[8];
    float* loss = (float*)d_out;

    const int n_nodes = in_sizes[0] / D_FEAT;
    const int n_edges = in_sizes[1] / 2;
    const int* src = ei;
    const int* dst = ei + n_edges;

    const int nbuckets = (n_nodes + NPB - 1) / NPB;
    const int M = nbuckets * NCHUNK;
    const int ept = (n_edges + NCHUNK - 1) / NCHUNK;

    size_t off = 0;
    auto alloc = [&](size_t bytes) {
        void* p = (char*)d_ws + off;
        off = (off + bytes + 255) & ~(size_t)255;
        return p;
    };
    int*            counts = (int*)alloc((size_t)(M + 1) * 4);
    int*            totals = (int*)alloc((size_t)MAXB * 4);
    int*            bbase  = (int*)alloc((size_t)MAXB * 4);
    unsigned*       packed = (unsigned*)alloc((size_t)n_edges * 4);
    int*            rowptr = (int*)alloc((size_t)(n_nodes + 1) * 4);
    int*            csr    = (int*)alloc((size_t)n_edges * 4);
    unsigned*       xr8    = (unsigned*)alloc((size_t)n_nodes * 32);      // fp8 [n][32]
    float*          xroot  = (float*)alloc((size_t)n_nodes * H_SIZE * 4);
    __hip_bfloat16* h2     = (__hip_bfloat16*)alloc((size_t)n_nodes * 16 * 2);
    float*          hroot  = (float*)alloc((size_t)n_nodes * 16 * 4);

    // dense pre-transform via MFMA (64 nodes/block)
    dense1_mfma<<<(n_nodes + 63) / 64, NT, 0, stream>>>(
        x, W1_rel, b1_rel, W1_root, xr8, xroot, n_nodes);

    // bucket build -> packed -> CSR
    bucket_count<<<NCHUNK, BT, 0, stream>>>(dst, counts, n_edges, nbuckets, ept);
    bucket_totals<<<nbuckets, NPB, 0, stream>>>(counts, totals);
    scan_small<<<1, MAXB, 0, stream>>>(totals, bbase, nbuckets);
    scan_within<<<nbuckets, NPB, 0, stream>>>(counts, bbase);
    bucket_scatter<<<NCHUNK, BT, 0, stream>>>(src, dst, counts, packed,
                                              n_edges, nbuckets, ept);
    csr_build<<<nbuckets, NPB, 0, stream>>>(packed, counts, rowptr, csr,
                                            n_nodes, nbuckets, n_edges);

    // layer 1 aggregate + fused dense2 (128 nodes per block, 2 lanes/node)
    gather1_kernel<<<(n_nodes + 127) / 128, NT, 0, stream>>>(
        (const uint4v*)xr8, xroot, rowptr, csr,
        W2_rel, b2_rel, W2_root, h2, hroot, n_nodes);

    // layer 2 aggregate + loss (128 nodes per block, 2 lanes/node)
    hipMemsetAsync(loss, 0, sizeof(float), stream);
    gather2_loss_kernel<<<(n_nodes + 127) / 128, NT, 0, stream>>>(
        (const uint4v*)h2, hroot, rowptr, csr, y, loss,
        n_nodes, 1.f / (float)n_nodes);
}

// Round 14
// 199.785 us; speedup vs baseline: 1.0239x; 1.0239x over previous
//
#include <hip/hip_runtime.h>
#include <hip/hip_bf16.h>
#include <hip/hip_fp8.h>

#define D_FEAT 64
#define H_SIZE 32
#define N_CLASSES 10
#define NPB 128          // nodes per bucket (bucket = dst >> 7)
#define MAXB 1024        // max buckets supported
#define NCHUNK 512       // edge chunks for count/scatter passes
#define BT 1024
#define NT 256
#define NTG 64           // gather block size (1 wave)
#define GNODES 32        // nodes per gather block (2 lanes/node)

using short8 = __attribute__((ext_vector_type(8))) short;
using f32x4v = __attribute__((ext_vector_type(4))) float;

__device__ inline short f2bf(float f) {
    __hip_bfloat16 h = __float2bfloat16(f);
    return *reinterpret_cast<short*>(&h);
}

// fp8 byte -> float
#define F8(u, s) ({ __hip_fp8_e4m3 _f; _f.__x = (unsigned char)(((u) >> (s)) & 0xff); (float)_f; })

#define ACC16(p) do { \
    a[0]  += F8((p).x, 0);  a[1]  += F8((p).x, 8);  a[2]  += F8((p).x, 16); a[3]  += F8((p).x, 24); \
    a[4]  += F8((p).y, 0);  a[5]  += F8((p).y, 8);  a[6]  += F8((p).y, 16); a[7]  += F8((p).y, 24); \
    a[8]  += F8((p).z, 0);  a[9]  += F8((p).z, 8);  a[10] += F8((p).z, 16); a[11] += F8((p).z, 24); \
    a[12] += F8((p).w, 0);  a[13] += F8((p).w, 8);  a[14] += F8((p).w, 16); a[15] += F8((p).w, 24); } while (0)

#define ACC8(p) do { \
    a[0] += __uint_as_float((p).x << 16); a[1] += __uint_as_float((p).x & 0xFFFF0000u); \
    a[2] += __uint_as_float((p).y << 16); a[3] += __uint_as_float((p).y & 0xFFFF0000u); \
    a[4] += __uint_as_float((p).z << 16); a[5] += __uint_as_float((p).z & 0xFFFF0000u); \
    a[6] += __uint_as_float((p).w << 16); a[7] += __uint_as_float((p).w & 0xFFFF0000u); } while (0)

// ---------- dense1 via MFMA: O = x @ [W1_rel^T | W1_root^T] ---------------

__global__ __launch_bounds__(NT) void dense1_mfma(
    const float* __restrict__ x, const float* __restrict__ W1_rel,
    const float* __restrict__ b1, const float* __restrict__ W1_root,
    unsigned* __restrict__ xr8, float* __restrict__ xroot, int n_nodes) {
    __shared__ unsigned short sW[64 * 72];   // [outcol n][k] bf16, pad 72
    __shared__ float sOut[64 * 65];          // [node][outcol] f32, pad 65
    __shared__ float sb[H_SIZE];
    int tid = threadIdx.x;
    for (int i = tid; i < 64 * 64; i += NT) {
        int n = i >> 6, k = i & 63;
        float w = (n < 32) ? W1_rel[n * 64 + k] : W1_root[(n - 32) * 64 + k];
        sW[n * 72 + k] = (unsigned short)f2bf(w);
    }
    if (tid < H_SIZE) sb[tid] = b1[tid];
    __syncthreads();

    int lane = tid & 63, wave = tid >> 6;
    int r16 = lane & 15, h = lane >> 4;

    short8 bf[4][2];
#pragma unroll
    for (int t = 0; t < 4; ++t)
#pragma unroll
        for (int s = 0; s < 2; ++s) {
            const unsigned short* p = &sW[(t * 16 + r16) * 72 + s * 32 + h * 8];
            bf[t][s] = *reinterpret_cast<const short8*>(p);
        }

    int nbase = blockIdx.x * 64 + wave * 16;
    int row = nbase + r16;
    int rowc = min(row, n_nodes - 1);

    short8 af[2];
#pragma unroll
    for (int s = 0; s < 2; ++s) {
        const float* px = x + (size_t)rowc * D_FEAT + s * 32 + h * 8;
        float4 lo = *reinterpret_cast<const float4*>(px);
        float4 hi = *reinterpret_cast<const float4*>(px + 4);
        short8 a;
        a[0] = f2bf(lo.x); a[1] = f2bf(lo.y); a[2] = f2bf(lo.z); a[3] = f2bf(lo.w);
        a[4] = f2bf(hi.x); a[5] = f2bf(hi.y); a[6] = f2bf(hi.z); a[7] = f2bf(hi.w);
        af[s] = a;
    }

    f32x4v acc[4] = {{0.f,0.f,0.f,0.f},{0.f,0.f,0.f,0.f},
                     {0.f,0.f,0.f,0.f},{0.f,0.f,0.f,0.f}};
#pragma unroll
    for (int t = 0; t < 4; ++t) {
        acc[t] = __builtin_amdgcn_mfma_f32_16x16x32_bf16(af[0], bf[t][0], acc[t], 0, 0, 0);
        acc[t] = __builtin_amdgcn_mfma_f32_16x16x32_bf16(af[1], bf[t][1], acc[t], 0, 0, 0);
    }
#pragma unroll
    for (int t = 0; t < 4; ++t)
#pragma unroll
        for (int r = 0; r < 4; ++r)
            sOut[(wave * 16 + h * 4 + r) * 65 + t * 16 + r16] = acc[t][r];
    __syncthreads();

    int nl = lane;
    int g = blockIdx.x * 64 + nl;
    if (g < n_nodes) {
        if (wave < 2) {
            unsigned w4[4];
#pragma unroll
            for (int q = 0; q < 4; ++q) {
                unsigned wd = 0;
#pragma unroll
                for (int b = 0; b < 4; ++b) {
                    float v = sOut[nl * 65 + wave * 16 + q * 4 + b];
                    __hip_fp8_e4m3 f8(v);
                    wd |= ((unsigned)f8.__x) << (8 * b);
                }
                w4[q] = wd;
            }
            *reinterpret_cast<uint4*>(&xr8[(size_t)g * 8 + wave * 4]) =
                make_uint4(w4[0], w4[1], w4[2], w4[3]);
        } else {
            int co = (wave - 2) * 16;
#pragma unroll
            for (int q = 0; q < 4; ++q) {
                float4 v;
                v.x = sOut[nl * 65 + 32 + co + q * 4 + 0] + sb[co + q * 4 + 0];
                v.y = sOut[nl * 65 + 32 + co + q * 4 + 1] + sb[co + q * 4 + 1];
                v.z = sOut[nl * 65 + 32 + co + q * 4 + 2] + sb[co + q * 4 + 2];
                v.w = sOut[nl * 65 + 32 + co + q * 4 + 3] + sb[co + q * 4 + 3];
                *reinterpret_cast<float4*>(&xroot[(size_t)g * 32 + co + q * 4]) = v;
            }
        }
    }
}

// ---------- bucket count -> hierarchical scan -> scatter -------------------

__global__ __launch_bounds__(BT) void bucket_count(
    const int* __restrict__ dst, int* __restrict__ counts,
    int n_edges, int nbuckets, int ept) {
    __shared__ int hist[MAXB];
    for (int i = threadIdx.x; i < nbuckets; i += BT) hist[i] = 0;
    __syncthreads();
    int beg = blockIdx.x * ept;
    int end = min(beg + ept, n_edges);
    for (int e = beg + threadIdx.x; e < end; e += BT)
        atomicAdd(&hist[dst[e] >> 7], 1);
    __syncthreads();
    for (int b = threadIdx.x; b < nbuckets; b += BT)
        counts[b * NCHUNK + blockIdx.x] = hist[b];
}

// per-bucket totals over NCHUNK chunk counts (one block of NCHUNK threads)
__global__ __launch_bounds__(NCHUNK) void bucket_totals(
    const int* __restrict__ counts, int* __restrict__ totals) {
    int b = blockIdx.x, tid = threadIdx.x;
    int v = counts[b * NCHUNK + tid];
#pragma unroll
    for (int o = 32; o > 0; o >>= 1) v += __shfl_down(v, o, 64);
    __shared__ int part[NCHUNK / 64];
    if ((tid & 63) == 0) part[tid >> 6] = v;
    __syncthreads();
    if (tid == 0) {
        int s = 0;
#pragma unroll
        for (int w = 0; w < NCHUNK / 64; ++w) s += part[w];
        totals[b] = s;
    }
}

__global__ __launch_bounds__(MAXB) void scan_small(
    const int* __restrict__ totals, int* __restrict__ bbase, int nbuckets) {
    __shared__ int lds[MAXB];
    int tid = threadIdx.x;
    int v = (tid < nbuckets) ? totals[tid] : 0;
    lds[tid] = v;
    __syncthreads();
    for (int off = 1; off < MAXB; off <<= 1) {
        int t = (tid >= off) ? lds[tid - off] : 0;
        __syncthreads();
        lds[tid] += t;
        __syncthreads();
    }
    if (tid < nbuckets) bbase[tid] = lds[tid] - v;
}

// per-bucket exclusive scan of NCHUNK chunk counts + bucket base (in place)
__global__ __launch_bounds__(NCHUNK) void scan_within(
    int* __restrict__ counts, const int* __restrict__ bbase) {
    __shared__ int lds[NCHUNK];
    int b = blockIdx.x, tid = threadIdx.x;
    int v = counts[b * NCHUNK + tid];
    lds[tid] = v;
    __syncthreads();
    for (int off = 1; off < NCHUNK; off <<= 1) {
        int t = (tid >= off) ? lds[tid - off] : 0;
        __syncthreads();
        lds[tid] += t;
        __syncthreads();
    }
    counts[b * NCHUNK + tid] = bbase[b] + lds[tid] - v;
}

__global__ __launch_bounds__(BT) void bucket_scatter(
    const int* __restrict__ src, const int* __restrict__ dst,
    const int* __restrict__ base, unsigned* __restrict__ packed,
    int n_edges, int nbuckets, int ept) {
    __shared__ int cur[MAXB];
    for (int b = threadIdx.x; b < nbuckets; b += BT)
        cur[b] = base[b * NCHUNK + blockIdx.x];
    __syncthreads();
    int beg = blockIdx.x * ept;
    int end = min(beg + ept, n_edges);
    for (int e = beg + threadIdx.x; e < end; e += BT) {
        int s = src[e], d = dst[e];
        int slot = atomicAdd(&cur[d >> 7], 1);
        packed[slot] = (unsigned)s | ((unsigned)(d & 127) << 24);
    }
}

// ---------- per-bucket counting sort -> global CSR -------------------------

__global__ __launch_bounds__(NPB) void csr_build(
    const unsigned* __restrict__ packed, const int* __restrict__ base,
    int* __restrict__ rowptr, int* __restrict__ csr,
    int n_nodes, int nbuckets, int n_edges) {
    __shared__ int cnt[NPB];
    __shared__ int cur[NPB];
    int b = blockIdx.x, tid = threadIdx.x;
    int pBeg = base[b * NCHUNK];
    int pEnd = (b + 1 < nbuckets) ? base[(b + 1) * NCHUNK] : n_edges;
    cnt[tid] = 0;
    __syncthreads();
    for (int i = pBeg + tid; i < pEnd; i += NPB)
        atomicAdd(&cnt[packed[i] >> 24], 1);
    __syncthreads();
    int v = cnt[tid];
    cur[tid] = v;
    __syncthreads();
    for (int off = 1; off < NPB; off <<= 1) {
        int t = (tid >= off) ? cur[tid - off] : 0;
        __syncthreads();
        cur[tid] += t;
        __syncthreads();
    }
    int gbase = pBeg + cur[tid] - v;
    int n = (b << 7) + tid;
    if (n < n_nodes) rowptr[n] = gbase;
    if (b == nbuckets - 1 && tid == 0) rowptr[n_nodes] = n_edges;
    cur[tid] = gbase;
    __syncthreads();
    for (int i = pBeg + tid; i < pEnd; i += NPB) {
        unsigned p = packed[i];
        int slot = atomicAdd(&cur[p >> 24], 1);
        csr[slot] = (int)(p & 0xFFFFFF);
    }
}

// ---------- gather1 (+fused dense2): 2 lanes/node, 1-wave blocks -----------

__global__ __launch_bounds__(NTG) void gather1_kernel(
    const uint4* __restrict__ xr8v,        // 2 uint4 per node row (32 fp8)
    const float* __restrict__ xroot,
    const int* __restrict__ rowptr, const int* __restrict__ csr,
    const float* __restrict__ W2_rel, const float* __restrict__ b2,
    const float* __restrict__ W2_root,
    __hip_bfloat16* __restrict__ h2, float* __restrict__ hroot, int n_nodes) {
    __shared__ float sWrelT[H_SIZE * 17];  // [j][c] stride 17
    __shared__ float sWrootT[H_SIZE * 17];
    __shared__ float sb[16];
    __shared__ float sh[GNODES][33];       // 32 nodes/block
    int tid = threadIdx.x;
    for (int i = tid; i < H_SIZE * 17; i += NTG) { sWrelT[i] = 0.f; sWrootT[i] = 0.f; }
    __syncthreads();
    for (int i = tid; i < N_CLASSES * H_SIZE; i += NTG) {
        int c = i >> 5, j = i & 31;
        sWrelT[j * 17 + c] = W2_rel[i];
        sWrootT[j * 17 + c] = W2_root[i];
    }
    if (tid < 16) sb[tid] = (tid < N_CLASSES) ? b2[tid] : 0.f;

    int t = blockIdx.x * NTG + tid;
    int n = t >> 1, c1 = t & 1;            // 2 lanes/node; c1 = 16-feat half
    float a[16] = {0.f,0.f,0.f,0.f,0.f,0.f,0.f,0.f,
                   0.f,0.f,0.f,0.f,0.f,0.f,0.f,0.f};
    if (n < n_nodes) {
        int beg = rowptr[n], end = rowptr[n + 1];
        int i = beg;
        for (; i + 4 <= end; i += 4) {     // 4 edges/iter, 4 row loads in flight
            int e0 = csr[i + c1];
            int e1 = csr[i + 2 + c1];
            uint4 p0 = xr8v[(size_t)__shfl(e0, 0, 2) * 2 + c1];
            uint4 p1 = xr8v[(size_t)__shfl(e0, 1, 2) * 2 + c1];
            uint4 p2 = xr8v[(size_t)__shfl(e1, 0, 2) * 2 + c1];
            uint4 p3 = xr8v[(size_t)__shfl(e1, 1, 2) * 2 + c1];
            ACC16(p0); ACC16(p1); ACC16(p2); ACC16(p3);
        }
        if (i + 2 <= end) {
            int e0 = csr[i + c1];
            uint4 p0 = xr8v[(size_t)__shfl(e0, 0, 2) * 2 + c1];
            uint4 p1 = xr8v[(size_t)__shfl(e0, 1, 2) * 2 + c1];
            ACC16(p0); ACC16(p1);
            i += 2;
        }
        if (i < end) {
            int e = csr[i];
            uint4 p = xr8v[(size_t)e * 2 + c1];
            ACC16(p);
        }
        const float4* xr4 = reinterpret_cast<const float4*>(
            xroot + (size_t)n * 32 + c1 * 16);
#pragma unroll
        for (int q = 0; q < 4; ++q) {
            float4 v = xr4[q];
            a[q * 4 + 0] = fmaxf(a[q * 4 + 0] + v.x, 0.f);
            a[q * 4 + 1] = fmaxf(a[q * 4 + 1] + v.y, 0.f);
            a[q * 4 + 2] = fmaxf(a[q * 4 + 2] + v.z, 0.f);
            a[q * 4 + 3] = fmaxf(a[q * 4 + 3] + v.w, 0.f);
        }
    }
    int nl = tid >> 1;
#pragma unroll
    for (int j = 0; j < 16; ++j) sh[nl][c1 * 16 + j] = a[j];
    __syncthreads();

    // fused dense2: 32 nodes x 16 cols = 512 items, 8 passes of 64
#pragma unroll
    for (int pass = 0; pass < 8; ++pass) {
        int idx = pass * NTG + tid;
        int nl2 = idx >> 4, c = idx & 15;
        int n2 = blockIdx.x * GNODES + nl2;
        if (n2 < n_nodes) {
            float ar = 0.f, ao = 0.f;
#pragma unroll
            for (int j = 0; j < H_SIZE; ++j) {
                float hv = sh[nl2][j];
                ar += hv * sWrelT[j * 17 + c];
                ao += hv * sWrootT[j * 17 + c];
            }
            h2[(size_t)n2 * 16 + c] = __float2bfloat16(ar);
            hroot[(size_t)n2 * 16 + c] = ao + sb[c];
        }
    }
}

// ---------- gather2 + loss: 2 lanes/node, 1-wave blocks --------------------

__global__ __launch_bounds__(NTG) void gather2_loss_kernel(
    const uint4* __restrict__ h2v,         // 2 uint4 per node row (16 bf16)
    const float* __restrict__ hroot,
    const int* __restrict__ rowptr, const int* __restrict__ csr,
    const int* __restrict__ y, float* __restrict__ loss,
    int n_nodes, float invN) {
    int t = blockIdx.x * NTG + threadIdx.x;
    int n = t >> 1, c1 = t & 1;            // c1 = 8-class half
    int lane = threadIdx.x & 63;
    bool active = (n < n_nodes);

    float a[8] = {0.f,0.f,0.f,0.f,0.f,0.f,0.f,0.f};
    int yv = 0;
    if (active) {
        int beg = rowptr[n], end = rowptr[n + 1];
        int i = beg;
        for (; i + 4 <= end; i += 4) {
            int e0 = csr[i + c1];
            int e1 = csr[i + 2 + c1];
            uint4 p0 = h2v[(size_t)__shfl(e0, 0, 2) * 2 + c1];
            uint4 p1 = h2v[(size_t)__shfl(e0, 1, 2) * 2 + c1];
            uint4 p2 = h2v[(size_t)__shfl(e1, 0, 2) * 2 + c1];
            uint4 p3 = h2v[(size_t)__shfl(e1, 1, 2) * 2 + c1];
            ACC8(p0); ACC8(p1); ACC8(p2); ACC8(p3);
        }
        if (i + 2 <= end) {
            int e0 = csr[i + c1];
            uint4 p0 = h2v[(size_t)__shfl(e0, 0, 2) * 2 + c1];
            uint4 p1 = h2v[(size_t)__shfl(e0, 1, 2) * 2 + c1];
            ACC8(p0); ACC8(p1);
            i += 2;
        }
        if (i < end) {
            int e = csr[i];
            uint4 p = h2v[(size_t)e * 2 + c1];
            ACC8(p);
        }
        const float4* hr4 = reinterpret_cast<const float4*>(
            hroot + (size_t)n * 16 + c1 * 8);
        float4 h0 = hr4[0], h1 = hr4[1];
        a[0] += h0.x; a[1] += h0.y; a[2] += h0.z; a[3] += h0.w;
        a[4] += h1.x; a[5] += h1.y; a[6] += h1.z; a[7] += h1.w;
        yv = y[n];
    }
    // log-softmax: lane c1=0 holds classes 0..7, lane c1=1 holds 8..15 (8,9 valid)
    bool full = active && (c1 == 0);
    float m = -INFINITY;
#pragma unroll
    for (int j = 0; j < 8; ++j) {
        bool v = (j < 2) ? active : full;
        m = fmaxf(m, v ? a[j] : -INFINITY);
    }
    m = fmaxf(m, __shfl_xor(m, 1, 64));
    float es = 0.f;
#pragma unroll
    for (int j = 0; j < 8; ++j) {
        bool v = (j < 2) ? active : full;
        es += v ? expf(a[j] - m) : 0.f;
    }
    es += __shfl_xor(es, 1, 64);
    int yl = yv & 7;
    float lyc = 0.f;
#pragma unroll
    for (int j = 0; j < 8; ++j) lyc = (j == yl) ? a[j] : lyc;
    float ly = __shfl(lyc, (lane & ~1) + (yv >> 3), 64);
    float contrib = (active && c1 == 0) ? (m + logf(es) - ly) * invN : 0.f;

#pragma unroll
    for (int o = 32; o > 0; o >>= 1) contrib += __shfl_down(contrib, o, 64);
    if (threadIdx.x == 0) atomicAdd(loss, contrib);
}

// ---------------------------------------------------------------------------

extern "C" void kernel_launch(void* const* d_in, const int* in_sizes, int n_in,
                              void* d_out, int out_size, void* d_ws, size_t ws_size,
                              hipStream_t stream) {
    const float* x       = (const float*)d_in[0];
    const int*   ei      = (const int*)d_in[1];
    const int*   y       = (const int*)d_in[2];
    const float* W1_rel  = (const float*)d_in[3];
    const float* b1_rel  = (const float*)d_in[4];
    const float* W1_root = (const float*)d_in[5];
    const float* W2_rel  = (const float*)d_in[6];
    const float* b2_rel  = (const float*)d_in[7];
    const float* W2_root = (const float*)d_in[8];
    float* loss = (float*)d_out;

    const int n_nodes = in_sizes[0] / D_FEAT;
    const int n_edges = in_sizes[1] / 2;
    const int* src = ei;
    const int* dst = ei + n_edges;

    const int nbuckets = (n_nodes + NPB - 1) / NPB;       // 782
    const int M = nbuckets * NCHUNK;
    const int ept = (n_edges + NCHUNK - 1) / NCHUNK;      // ~6250

    size_t off = 0;
    auto alloc = [&](size_t bytes) {
        void* p = (char*)d_ws + off;
        off = (off + bytes + 255) & ~(size_t)255;
        return p;
    };
    int*            counts = (int*)alloc((size_t)(M + 1) * 4);
    int*            totals = (int*)alloc((size_t)MAXB * 4);
    int*            bbase  = (int*)alloc((size_t)MAXB * 4);
    unsigned*       packed = (unsigned*)alloc((size_t)n_edges * 4);
    int*            rowptr = (int*)alloc((size_t)(n_nodes + 1) * 4);
    int*            csr    = (int*)alloc((size_t)n_edges * 4);
    unsigned*       xr8    = (unsigned*)alloc((size_t)n_nodes * 32);      // fp8 [n][32]
    float*          xroot  = (float*)alloc((size_t)n_nodes * H_SIZE * 4);
    __hip_bfloat16* h2     = (__hip_bfloat16*)alloc((size_t)n_nodes * 16 * 2);
    float*          hroot  = (float*)alloc((size_t)n_nodes * 16 * 4);

    // dense pre-transform via MFMA (64 nodes/block)
    dense1_mfma<<<(n_nodes + 63) / 64, NT, 0, stream>>>(
        x, W1_rel, b1_rel, W1_root, xr8, xroot, n_nodes);

    // bucket build -> packed -> CSR
    bucket_count<<<NCHUNK, BT, 0, stream>>>(dst, counts, n_edges, nbuckets, ept);
    bucket_totals<<<nbuckets, NCHUNK, 0, stream>>>(counts, totals);
    scan_small<<<1, MAXB, 0, stream>>>(totals, bbase, nbuckets);
    scan_within<<<nbuckets, NCHUNK, 0, stream>>>(counts, bbase);
    bucket_scatter<<<NCHUNK, BT, 0, stream>>>(src, dst, counts, packed,
                                              n_edges, nbuckets, ept);
    csr_build<<<nbuckets, NPB, 0, stream>>>(packed, counts, rowptr, csr,
                                            n_nodes, nbuckets, n_edges);

    // layer 1 aggregate + fused dense2 (32 nodes/block, 1-wave blocks)
    gather1_kernel<<<(n_nodes + GNODES - 1) / GNODES, NTG, 0, stream>>>(
        (const uint4*)xr8, xroot, rowptr, csr,
        W2_rel, b2_rel, W2_root, h2, hroot, n_nodes);

    // layer 2 aggregate + loss (32 nodes/block, 1-wave blocks)
    hipMemsetAsync(loss, 0, sizeof(float), stream);
    gather2_loss_kernel<<<(n_nodes + GNODES - 1) / GNODES, NTG, 0, stream>>>(
        (const uint4*)h2, hroot, rowptr, csr, y, loss,
        n_nodes, 1.f / (float)n_nodes);
}

// Round 15
// 162.380 us; speedup vs baseline: 1.2598x; 1.2304x over previous
//
#include <hip/hip_runtime.h>
#include <hip/hip_bf16.h>
#include <hip/hip_fp8.h>

#define D_FEAT 64
#define H_SIZE 32
#define N_CLASSES 10
#define NPB 256          // nodes per bucket (bucket = dst >> 8)
#define MAXB 512
#define NCHUNK 256       // edge chunks for count/scatter passes
#define BT 1024
#define NT 256
#define CSR_CAP 12032    // csr_build LDS cache entries (47 KB; mean bucket ~8184)

using short8 = __attribute__((ext_vector_type(8))) short;
using f32x4v = __attribute__((ext_vector_type(4))) float;

__device__ inline short f2bf(float f) {
    __hip_bfloat16 h = __float2bfloat16(f);
    return *reinterpret_cast<short*>(&h);
}

// fp8 byte -> float
#define F8(u, s) ({ __hip_fp8_e4m3 _f; _f.__x = (unsigned char)(((u) >> (s)) & 0xff); (float)_f; })

#define ACC16(p) do { \
    a[0]  += F8((p).x, 0);  a[1]  += F8((p).x, 8);  a[2]  += F8((p).x, 16); a[3]  += F8((p).x, 24); \
    a[4]  += F8((p).y, 0);  a[5]  += F8((p).y, 8);  a[6]  += F8((p).y, 16); a[7]  += F8((p).y, 24); \
    a[8]  += F8((p).z, 0);  a[9]  += F8((p).z, 8);  a[10] += F8((p).z, 16); a[11] += F8((p).z, 24); \
    a[12] += F8((p).w, 0);  a[13] += F8((p).w, 8);  a[14] += F8((p).w, 16); a[15] += F8((p).w, 24); } while (0)

#define ACC8(p) do { \
    a[0] += __uint_as_float((p).x << 16); a[1] += __uint_as_float((p).x & 0xFFFF0000u); \
    a[2] += __uint_as_float((p).y << 16); a[3] += __uint_as_float((p).y & 0xFFFF0000u); \
    a[4] += __uint_as_float((p).z << 16); a[5] += __uint_as_float((p).z & 0xFFFF0000u); \
    a[6] += __uint_as_float((p).w << 16); a[7] += __uint_as_float((p).w & 0xFFFF0000u); } while (0)

// ---------- dense1 via MFMA: O = x @ [W1_rel^T | W1_root^T] ---------------

__global__ __launch_bounds__(NT) void dense1_mfma(
    const float* __restrict__ x, const float* __restrict__ W1_rel,
    const float* __restrict__ b1, const float* __restrict__ W1_root,
    unsigned* __restrict__ xr8, float* __restrict__ xroot, int n_nodes) {
    __shared__ unsigned short sW[64 * 72];   // [outcol n][k] bf16, pad 72
    __shared__ float sOut[64 * 65];          // [node][outcol] f32, pad 65
    __shared__ float sb[H_SIZE];
    int tid = threadIdx.x;
    for (int i = tid; i < 64 * 64; i += NT) {
        int n = i >> 6, k = i & 63;
        float w = (n < 32) ? W1_rel[n * 64 + k] : W1_root[(n - 32) * 64 + k];
        sW[n * 72 + k] = (unsigned short)f2bf(w);
    }
    if (tid < H_SIZE) sb[tid] = b1[tid];
    __syncthreads();

    int lane = tid & 63, wave = tid >> 6;
    int r16 = lane & 15, h = lane >> 4;

    short8 bf[4][2];
#pragma unroll
    for (int t = 0; t < 4; ++t)
#pragma unroll
        for (int s = 0; s < 2; ++s) {
            const unsigned short* p = &sW[(t * 16 + r16) * 72 + s * 32 + h * 8];
            bf[t][s] = *reinterpret_cast<const short8*>(p);
        }

    int nbase = blockIdx.x * 64 + wave * 16;
    int row = nbase + r16;
    int rowc = min(row, n_nodes - 1);

    short8 af[2];
#pragma unroll
    for (int s = 0; s < 2; ++s) {
        const float* px = x + (size_t)rowc * D_FEAT + s * 32 + h * 8;
        float4 lo = *reinterpret_cast<const float4*>(px);
        float4 hi = *reinterpret_cast<const float4*>(px + 4);
        short8 a;
        a[0] = f2bf(lo.x); a[1] = f2bf(lo.y); a[2] = f2bf(lo.z); a[3] = f2bf(lo.w);
        a[4] = f2bf(hi.x); a[5] = f2bf(hi.y); a[6] = f2bf(hi.z); a[7] = f2bf(hi.w);
        af[s] = a;
    }

    f32x4v acc[4] = {{0.f,0.f,0.f,0.f},{0.f,0.f,0.f,0.f},
                     {0.f,0.f,0.f,0.f},{0.f,0.f,0.f,0.f}};
#pragma unroll
    for (int t = 0; t < 4; ++t) {
        acc[t] = __builtin_amdgcn_mfma_f32_16x16x32_bf16(af[0], bf[t][0], acc[t], 0, 0, 0);
        acc[t] = __builtin_amdgcn_mfma_f32_16x16x32_bf16(af[1], bf[t][1], acc[t], 0, 0, 0);
    }
#pragma unroll
    for (int t = 0; t < 4; ++t)
#pragma unroll
        for (int r = 0; r < 4; ++r)
            sOut[(wave * 16 + h * 4 + r) * 65 + t * 16 + r16] = acc[t][r];
    __syncthreads();

    int nl = lane;
    int g = blockIdx.x * 64 + nl;
    if (g < n_nodes) {
        if (wave < 2) {
            unsigned w4[4];
#pragma unroll
            for (int q = 0; q < 4; ++q) {
                unsigned wd = 0;
#pragma unroll
                for (int b = 0; b < 4; ++b) {
                    float v = sOut[nl * 65 + wave * 16 + q * 4 + b];
                    __hip_fp8_e4m3 f8(v);
                    wd |= ((unsigned)f8.__x) << (8 * b);
                }
                w4[q] = wd;
            }
            *reinterpret_cast<uint4*>(&xr8[(size_t)g * 8 + wave * 4]) =
                make_uint4(w4[0], w4[1], w4[2], w4[3]);
        } else {
            int co = (wave - 2) * 16;
#pragma unroll
            for (int q = 0; q < 4; ++q) {
                float4 v;
                v.x = sOut[nl * 65 + 32 + co + q * 4 + 0] + sb[co + q * 4 + 0];
                v.y = sOut[nl * 65 + 32 + co + q * 4 + 1] + sb[co + q * 4 + 1];
                v.z = sOut[nl * 65 + 32 + co + q * 4 + 2] + sb[co + q * 4 + 2];
                v.w = sOut[nl * 65 + 32 + co + q * 4 + 3] + sb[co + q * 4 + 3];
                *reinterpret_cast<float4*>(&xroot[(size_t)g * 32 + co + q * 4]) = v;
            }
        }
    }
}

// ---------- bucket count (fused totals) -> scans -> scatter ----------------

__global__ __launch_bounds__(BT) void bucket_count(
    const int* __restrict__ dst, int* __restrict__ counts,
    int* __restrict__ totals, int n_edges, int nbuckets, int ept) {
    __shared__ int hist[MAXB];
    for (int i = threadIdx.x; i < nbuckets; i += BT) hist[i] = 0;
    __syncthreads();
    int beg = blockIdx.x * ept;
    int end = min(beg + ept, n_edges);
    for (int e = beg + threadIdx.x; e < end; e += BT)
        atomicAdd(&hist[dst[e] >> 8], 1);
    __syncthreads();
    for (int b = threadIdx.x; b < nbuckets; b += BT) {
        int h = hist[b];
        counts[b * NCHUNK + blockIdx.x] = h;
        if (h) atomicAdd(&totals[b], h);       // fused bucket_totals
    }
}

__global__ __launch_bounds__(MAXB) void scan_small(
    const int* __restrict__ totals, int* __restrict__ bbase, int nbuckets) {
    __shared__ int lds[MAXB];
    int tid = threadIdx.x;
    int v = (tid < nbuckets) ? totals[tid] : 0;
    lds[tid] = v;
    __syncthreads();
    for (int off = 1; off < MAXB; off <<= 1) {
        int t = (tid >= off) ? lds[tid - off] : 0;
        __syncthreads();
        lds[tid] += t;
        __syncthreads();
    }
    if (tid < nbuckets) bbase[tid] = lds[tid] - v;
}

__global__ __launch_bounds__(NPB) void scan_within(
    int* __restrict__ counts, const int* __restrict__ bbase) {
    __shared__ int lds[NPB];
    int b = blockIdx.x, tid = threadIdx.x;
    int v = counts[b * NCHUNK + tid];
    lds[tid] = v;
    __syncthreads();
    for (int off = 1; off < NPB; off <<= 1) {
        int t = (tid >= off) ? lds[tid - off] : 0;
        __syncthreads();
        lds[tid] += t;
        __syncthreads();
    }
    counts[b * NCHUNK + tid] = bbase[b] + lds[tid] - v;
}

__global__ __launch_bounds__(BT) void bucket_scatter(
    const int* __restrict__ src, const int* __restrict__ dst,
    const int* __restrict__ base, unsigned* __restrict__ packed,
    int n_edges, int nbuckets, int ept) {
    __shared__ int cur[MAXB];
    for (int b = threadIdx.x; b < nbuckets; b += BT)
        cur[b] = base[b * NCHUNK + blockIdx.x];
    __syncthreads();
    int beg = blockIdx.x * ept;
    int end = min(beg + ept, n_edges);
    for (int e = beg + threadIdx.x; e < end; e += BT) {
        int s = src[e], d = dst[e];
        int slot = atomicAdd(&cur[d >> 8], 1);
        packed[slot] = (unsigned)s | ((unsigned)(d & 255) << 24);
    }
}

// ---------- per-bucket counting sort -> global CSR (LDS-cached) ------------

__global__ __launch_bounds__(NPB) void csr_build(
    const unsigned* __restrict__ packed, const int* __restrict__ base,
    int* __restrict__ rowptr, int* __restrict__ csr,
    int n_nodes, int nbuckets, int n_edges) {
    __shared__ int cnt[NPB];
    __shared__ int cur[NPB];
    __shared__ unsigned cache[CSR_CAP];
    int b = blockIdx.x, tid = threadIdx.x;
    int pBeg = base[b * NCHUNK];
    int pEnd = (b + 1 < nbuckets) ? base[(b + 1) * NCHUNK] : n_edges;
    int sz = pEnd - pBeg;
    int m = min(sz, CSR_CAP);
    cnt[tid] = 0;
    for (int i = tid; i < m; i += NPB) cache[i] = packed[pBeg + i];
    __syncthreads();
    // pass 1: count (from LDS; global fallback for overflow)
    for (int i = tid; i < sz; i += NPB) {
        unsigned p = (i < m) ? cache[i] : packed[pBeg + i];
        atomicAdd(&cnt[p >> 24], 1);
    }
    __syncthreads();
    int v = cnt[tid];
    cur[tid] = v;
    __syncthreads();
    for (int off = 1; off < NPB; off <<= 1) {
        int t = (tid >= off) ? cur[tid - off] : 0;
        __syncthreads();
        cur[tid] += t;
        __syncthreads();
    }
    int gbase = pBeg + cur[tid] - v;
    int n = (b << 8) + tid;
    if (n < n_nodes) rowptr[n] = gbase;
    if (b == nbuckets - 1 && tid == 0) rowptr[n_nodes] = n_edges;
    cur[tid] = gbase;
    __syncthreads();
    // pass 2: scatter (from LDS)
    for (int i = tid; i < sz; i += NPB) {
        unsigned p = (i < m) ? cache[i] : packed[pBeg + i];
        int slot = atomicAdd(&cur[p >> 24], 1);
        csr[slot] = (int)(p & 0xFFFFFF);
    }
}

// ---------- gather1 (+fused dense2): 2 lanes/node, uint4 (16 fp8) loads ----

__global__ __launch_bounds__(NT) void gather1_kernel(
    const uint4* __restrict__ xr8v,        // 2 uint4 per node row (32 fp8)
    const float* __restrict__ xroot,
    const int* __restrict__ rowptr, const int* __restrict__ csr,
    const float* __restrict__ W2_rel, const float* __restrict__ b2,
    const float* __restrict__ W2_root,
    __hip_bfloat16* __restrict__ h2, float* __restrict__ hroot, int n_nodes) {
    __shared__ float sWrelT[H_SIZE * 17];  // [j][c] stride 17
    __shared__ float sWrootT[H_SIZE * 17];
    __shared__ float sb[16];
    __shared__ float sh[128][33];          // 128 nodes/block
    int tid = threadIdx.x;
    for (int i = tid; i < H_SIZE * 17; i += NT) { sWrelT[i] = 0.f; sWrootT[i] = 0.f; }
    __syncthreads();
    for (int i = tid; i < N_CLASSES * H_SIZE; i += NT) {
        int c = i >> 5, j = i & 31;
        sWrelT[j * 17 + c] = W2_rel[i];
        sWrootT[j * 17 + c] = W2_root[i];
    }
    if (tid < 16) sb[tid] = (tid < N_CLASSES) ? b2[tid] : 0.f;

    int t = blockIdx.x * NT + tid;
    int n = t >> 1, c1 = t & 1;            // 2 lanes/node; c1 = 16-feat half
    float a[16] = {0.f,0.f,0.f,0.f,0.f,0.f,0.f,0.f,
                   0.f,0.f,0.f,0.f,0.f,0.f,0.f,0.f};
    if (n < n_nodes) {
        int beg = rowptr[n], end = rowptr[n + 1];
        int i = beg;
        for (; i + 4 <= end; i += 4) {     // 4 edges per iter, 4 loads in flight
            int e0 = csr[i + c1];
            int e1 = csr[i + 2 + c1];
            uint4 p0 = xr8v[(size_t)__shfl(e0, 0, 2) * 2 + c1];
            uint4 p1 = xr8v[(size_t)__shfl(e0, 1, 2) * 2 + c1];
            uint4 p2 = xr8v[(size_t)__shfl(e1, 0, 2) * 2 + c1];
            uint4 p3 = xr8v[(size_t)__shfl(e1, 1, 2) * 2 + c1];
            ACC16(p0); ACC16(p1); ACC16(p2); ACC16(p3);
        }
        if (i + 2 <= end) {
            int e0 = csr[i + c1];
            uint4 p0 = xr8v[(size_t)__shfl(e0, 0, 2) * 2 + c1];
            uint4 p1 = xr8v[(size_t)__shfl(e0, 1, 2) * 2 + c1];
            ACC16(p0); ACC16(p1);
            i += 2;
        }
        if (i < end) {                     // single leftover edge (broadcast)
            int e = csr[i];
            uint4 p = xr8v[(size_t)e * 2 + c1];
            ACC16(p);
        }
        const float4* xr4 = reinterpret_cast<const float4*>(
            xroot + (size_t)n * 32 + c1 * 16);
#pragma unroll
        for (int q = 0; q < 4; ++q) {
            float4 v = xr4[q];
            a[q * 4 + 0] = fmaxf(a[q * 4 + 0] + v.x, 0.f);
            a[q * 4 + 1] = fmaxf(a[q * 4 + 1] + v.y, 0.f);
            a[q * 4 + 2] = fmaxf(a[q * 4 + 2] + v.z, 0.f);
            a[q * 4 + 3] = fmaxf(a[q * 4 + 3] + v.w, 0.f);
        }
    }
    int nl = tid >> 1;
#pragma unroll
    for (int j = 0; j < 16; ++j) sh[nl][c1 * 16 + j] = a[j];
    __syncthreads();

    // fused dense2: 128 nodes x 16 cols = 2048 items, 8 passes
#pragma unroll
    for (int pass = 0; pass < 8; ++pass) {
        int idx = pass * NT + tid;
        int nl2 = idx >> 4, c = idx & 15;
        int n2 = blockIdx.x * 128 + nl2;
        if (n2 < n_nodes) {
            float ar = 0.f, ao = 0.f;
#pragma unroll
            for (int j = 0; j < H_SIZE; ++j) {
                float hv = sh[nl2][j];
                ar += hv * sWrelT[j * 17 + c];
                ao += hv * sWrootT[j * 17 + c];
            }
            h2[(size_t)n2 * 16 + c] = __float2bfloat16(ar);
            hroot[(size_t)n2 * 16 + c] = ao + sb[c];
        }
    }
}

// ---------- gather2 + loss: 2 lanes/node, uint4 (8 bf16) loads -------------

__global__ __launch_bounds__(NT) void gather2_loss_kernel(
    const uint4* __restrict__ h2v,         // 2 uint4 per node row (16 bf16)
    const float* __restrict__ hroot,
    const int* __restrict__ rowptr, const int* __restrict__ csr,
    const int* __restrict__ y, float* __restrict__ loss,
    int n_nodes, float invN) {
    int t = blockIdx.x * NT + threadIdx.x;
    int n = t >> 1, c1 = t & 1;            // c1 = 8-class half
    int lane = threadIdx.x & 63;
    bool active = (n < n_nodes);

    float a[8] = {0.f,0.f,0.f,0.f,0.f,0.f,0.f,0.f};
    int yv = 0;
    if (active) {
        int beg = rowptr[n], end = rowptr[n + 1];
        int i = beg;
        for (; i + 4 <= end; i += 4) {
            int e0 = csr[i + c1];
            int e1 = csr[i + 2 + c1];
            uint4 p0 = h2v[(size_t)__shfl(e0, 0, 2) * 2 + c1];
            uint4 p1 = h2v[(size_t)__shfl(e0, 1, 2) * 2 + c1];
            uint4 p2 = h2v[(size_t)__shfl(e1, 0, 2) * 2 + c1];
            uint4 p3 = h2v[(size_t)__shfl(e1, 1, 2) * 2 + c1];
            ACC8(p0); ACC8(p1); ACC8(p2); ACC8(p3);
        }
        if (i + 2 <= end) {
            int e0 = csr[i + c1];
            uint4 p0 = h2v[(size_t)__shfl(e0, 0, 2) * 2 + c1];
            uint4 p1 = h2v[(size_t)__shfl(e0, 1, 2) * 2 + c1];
            ACC8(p0); ACC8(p1);
            i += 2;
        }
        if (i < end) {
            int e = csr[i];
            uint4 p = h2v[(size_t)e * 2 + c1];
            ACC8(p);
        }
        const float4* hr4 = reinterpret_cast<const float4*>(
            hroot + (size_t)n * 16 + c1 * 8);
        float4 h0 = hr4[0], h1 = hr4[1];
        a[0] += h0.x; a[1] += h0.y; a[2] += h0.z; a[3] += h0.w;
        a[4] += h1.x; a[5] += h1.y; a[6] += h1.z; a[7] += h1.w;
        yv = y[n];
    }
    // log-softmax: lane c1=0 holds classes 0..7, lane c1=1 holds 8..15 (8,9 valid)
    bool full = active && (c1 == 0);
    float m = -INFINITY;
#pragma unroll
    for (int j = 0; j < 8; ++j) {
        bool v = (j < 2) ? active : full;
        m = fmaxf(m, v ? a[j] : -INFINITY);
    }
    m = fmaxf(m, __shfl_xor(m, 1, 64));
    float es = 0.f;
#pragma unroll
    for (int j = 0; j < 8; ++j) {
        bool v = (j < 2) ? active : full;
        es += v ? expf(a[j] - m) : 0.f;
    }
    es += __shfl_xor(es, 1, 64);
    int yl = yv & 7;
    float lyc = 0.f;
#pragma unroll
    for (int j = 0; j < 8; ++j) lyc = (j == yl) ? a[j] : lyc;
    float ly = __shfl(lyc, (lane & ~1) + (yv >> 3), 64);
    float contrib = (active && c1 == 0) ? (m + logf(es) - ly) * invN : 0.f;

#pragma unroll
    for (int o = 32; o > 0; o >>= 1) contrib += __shfl_down(contrib, o, 64);
    __shared__ float part[NT / 64];
    if (lane == 0) part[threadIdx.x >> 6] = contrib;
    __syncthreads();
    if (threadIdx.x == 0) {
        float v = 0.f;
#pragma unroll
        for (int w = 0; w < NT / 64; ++w) v += part[w];
        atomicAdd(loss, v);
    }
}

// ---------------------------------------------------------------------------

extern "C" void kernel_launch(void* const* d_in, const int* in_sizes, int n_in,
                              void* d_out, int out_size, void* d_ws, size_t ws_size,
                              hipStream_t stream) {
    const float* x       = (const float*)d_in[0];
    const int*   ei      = (const int*)d_in[1];
    const int*   y       = (const int*)d_in[2];
    const float* W1_rel  = (const float*)d_in[3];
    const float* b1_rel  = (const float*)d_in[4];
    const float* W1_root = (const float*)d_in[5];
    const float* W2_rel  = (const float*)d_in[6];
    const float* b2_rel  = (const float*)d_in[7];
    const float* W2_root = (const float*)d_in[8];
    float* loss = (float*)d_out;

    const int n_nodes = in_sizes[0] / D_FEAT;
    const int n_edges = in_sizes[1] / 2;
    const int* src = ei;
    const int* dst = ei + n_edges;

    const int nbuckets = (n_nodes + NPB - 1) / NPB;
    const int M = nbuckets * NCHUNK;
    const int ept = (n_edges + NCHUNK - 1) / NCHUNK;

    size_t off = 0;
    auto alloc = [&](size_t bytes) {
        void* p = (char*)d_ws + off;
        off = (off + bytes + 255) & ~(size_t)255;
        return p;
    };
    int*            counts = (int*)alloc((size_t)(M + 1) * 4);
    int*            totals = (int*)alloc((size_t)MAXB * 4);
    int*            bbase  = (int*)alloc((size_t)MAXB * 4);
    unsigned*       packed = (unsigned*)alloc((size_t)n_edges * 4);
    int*            rowptr = (int*)alloc((size_t)(n_nodes + 1) * 4);
    int*            csr    = (int*)alloc((size_t)n_edges * 4);
    unsigned*       xr8    = (unsigned*)alloc((size_t)n_nodes * 32);      // fp8 [n][32]
    float*          xroot  = (float*)alloc((size_t)n_nodes * H_SIZE * 4);
    __hip_bfloat16* h2     = (__hip_bfloat16*)alloc((size_t)n_nodes * 16 * 2);
    float*          hroot  = (float*)alloc((size_t)n_nodes * 16 * 4);

    // dense pre-transform via MFMA (64 nodes/block)
    dense1_mfma<<<(n_nodes + 63) / 64, NT, 0, stream>>>(
        x, W1_rel, b1_rel, W1_root, xr8, xroot, n_nodes);

    // bucket build -> packed -> CSR
    hipMemsetAsync(totals, 0, (size_t)MAXB * 4, stream);
    bucket_count<<<NCHUNK, BT, 0, stream>>>(dst, counts, totals,
                                            n_edges, nbuckets, ept);
    scan_small<<<1, MAXB, 0, stream>>>(totals, bbase, nbuckets);
    scan_within<<<nbuckets, NPB, 0, stream>>>(counts, bbase);
    bucket_scatter<<<NCHUNK, BT, 0, stream>>>(src, dst, counts, packed,
                                              n_edges, nbuckets, ept);
    csr_build<<<nbuckets, NPB, 0, stream>>>(packed, counts, rowptr, csr,
                                            n_nodes, nbuckets, n_edges);

    // layer 1 aggregate + fused dense2 (128 nodes per block, 2 lanes/node)
    gather1_kernel<<<(n_nodes + 127) / 128, NT, 0, stream>>>(
        (const uint4*)xr8, xroot, rowptr, csr,
        W2_rel, b2_rel, W2_root, h2, hroot, n_nodes);

    // layer 2 aggregate + loss (128 nodes per block, 2 lanes/node)
    hipMemsetAsync(loss, 0, sizeof(float), stream);
    gather2_loss_kernel<<<(n_nodes + 127) / 128, NT, 0, stream>>>(
        (const uint4*)h2, hroot, rowptr, csr, y, loss,
        n_nodes, 1.f / (float)n_nodes);
}

// Round 16
// 158.738 us; speedup vs baseline: 1.2887x; 1.0229x over previous
//
#include <hip/hip_runtime.h>
#include <hip/hip_bf16.h>
#include <hip/hip_fp8.h>

#define D_FEAT 64
#define H_SIZE 32
#define N_CLASSES 10
#define NPB 256          // nodes per bucket (bucket = dst >> 8)
#define MAXB 512
#define NCHUNK 256       // edge chunks for count/scatter passes
#define BT 1024
#define NT 256
#define CSR_CAP 12032    // csr_build LDS cache entries

using short8 = __attribute__((ext_vector_type(8))) short;
using f32x4v = __attribute__((ext_vector_type(4))) float;

__device__ inline short f2bf(float f) {
    __hip_bfloat16 h = __float2bfloat16(f);
    return *reinterpret_cast<short*>(&h);
}

// fp8 byte -> float
#define F8(u, s) ({ __hip_fp8_e4m3 _f; _f.__x = (unsigned char)(((u) >> (s)) & 0xff); (float)_f; })

#define ACC16(p) do { \
    a[0]  += F8((p).x, 0);  a[1]  += F8((p).x, 8);  a[2]  += F8((p).x, 16); a[3]  += F8((p).x, 24); \
    a[4]  += F8((p).y, 0);  a[5]  += F8((p).y, 8);  a[6]  += F8((p).y, 16); a[7]  += F8((p).y, 24); \
    a[8]  += F8((p).z, 0);  a[9]  += F8((p).z, 8);  a[10] += F8((p).z, 16); a[11] += F8((p).z, 24); \
    a[12] += F8((p).w, 0);  a[13] += F8((p).w, 8);  a[14] += F8((p).w, 16); a[15] += F8((p).w, 24); } while (0)

#define ACC8(p) do { \
    a[0] += __uint_as_float((p).x << 16); a[1] += __uint_as_float((p).x & 0xFFFF0000u); \
    a[2] += __uint_as_float((p).y << 16); a[3] += __uint_as_float((p).y & 0xFFFF0000u); \
    a[4] += __uint_as_float((p).z << 16); a[5] += __uint_as_float((p).z & 0xFFFF0000u); \
    a[6] += __uint_as_float((p).w << 16); a[7] += __uint_as_float((p).w & 0xFFFF0000u); } while (0)

// ---------- dense1 via MFMA: O = x @ [W1_rel^T | W1_root^T] ---------------

__global__ __launch_bounds__(NT) void dense1_mfma(
    const float* __restrict__ x, const float* __restrict__ W1_rel,
    const float* __restrict__ b1, const float* __restrict__ W1_root,
    unsigned* __restrict__ xr8, float* __restrict__ xroot, int n_nodes) {
    __shared__ unsigned short sW[64 * 72];   // [outcol n][k] bf16, pad 72
    __shared__ float sOut[64 * 65];          // [node][outcol] f32, pad 65
    __shared__ float sb[H_SIZE];
    int tid = threadIdx.x;
    for (int i = tid; i < 64 * 64; i += NT) {
        int n = i >> 6, k = i & 63;
        float w = (n < 32) ? W1_rel[n * 64 + k] : W1_root[(n - 32) * 64 + k];
        sW[n * 72 + k] = (unsigned short)f2bf(w);
    }
    if (tid < H_SIZE) sb[tid] = b1[tid];
    __syncthreads();

    int lane = tid & 63, wave = tid >> 6;
    int r16 = lane & 15, h = lane >> 4;

    short8 bf[4][2];
#pragma unroll
    for (int t = 0; t < 4; ++t)
#pragma unroll
        for (int s = 0; s < 2; ++s) {
            const unsigned short* p = &sW[(t * 16 + r16) * 72 + s * 32 + h * 8];
            bf[t][s] = *reinterpret_cast<const short8*>(p);
        }

    int nbase = blockIdx.x * 64 + wave * 16;
    int row = nbase + r16;
    int rowc = min(row, n_nodes - 1);

    short8 af[2];
#pragma unroll
    for (int s = 0; s < 2; ++s) {
        const float* px = x + (size_t)rowc * D_FEAT + s * 32 + h * 8;
        float4 lo = *reinterpret_cast<const float4*>(px);
        float4 hi = *reinterpret_cast<const float4*>(px + 4);
        short8 a;
        a[0] = f2bf(lo.x); a[1] = f2bf(lo.y); a[2] = f2bf(lo.z); a[3] = f2bf(lo.w);
        a[4] = f2bf(hi.x); a[5] = f2bf(hi.y); a[6] = f2bf(hi.z); a[7] = f2bf(hi.w);
        af[s] = a;
    }

    f32x4v acc[4] = {{0.f,0.f,0.f,0.f},{0.f,0.f,0.f,0.f},
                     {0.f,0.f,0.f,0.f},{0.f,0.f,0.f,0.f}};
#pragma unroll
    for (int t = 0; t < 4; ++t) {
        acc[t] = __builtin_amdgcn_mfma_f32_16x16x32_bf16(af[0], bf[t][0], acc[t], 0, 0, 0);
        acc[t] = __builtin_amdgcn_mfma_f32_16x16x32_bf16(af[1], bf[t][1], acc[t], 0, 0, 0);
    }
#pragma unroll
    for (int t = 0; t < 4; ++t)
#pragma unroll
        for (int r = 0; r < 4; ++r)
            sOut[(wave * 16 + h * 4 + r) * 65 + t * 16 + r16] = acc[t][r];
    __syncthreads();

    int nl = lane;
    int g = blockIdx.x * 64 + nl;
    if (g < n_nodes) {
        if (wave < 2) {
            unsigned w4[4];
#pragma unroll
            for (int q = 0; q < 4; ++q) {
                unsigned wd = 0;
#pragma unroll
                for (int b = 0; b < 4; ++b) {
                    float v = sOut[nl * 65 + wave * 16 + q * 4 + b];
                    __hip_fp8_e4m3 f8(v);
                    wd |= ((unsigned)f8.__x) << (8 * b);
                }
                w4[q] = wd;
            }
            *reinterpret_cast<uint4*>(&xr8[(size_t)g * 8 + wave * 4]) =
                make_uint4(w4[0], w4[1], w4[2], w4[3]);
        } else {
            int co = (wave - 2) * 16;
#pragma unroll
            for (int q = 0; q < 4; ++q) {
                float4 v;
                v.x = sOut[nl * 65 + 32 + co + q * 4 + 0] + sb[co + q * 4 + 0];
                v.y = sOut[nl * 65 + 32 + co + q * 4 + 1] + sb[co + q * 4 + 1];
                v.z = sOut[nl * 65 + 32 + co + q * 4 + 2] + sb[co + q * 4 + 2];
                v.w = sOut[nl * 65 + 32 + co + q * 4 + 3] + sb[co + q * 4 + 3];
                *reinterpret_cast<float4*>(&xroot[(size_t)g * 32 + co + q * 4]) = v;
            }
        }
    }
}

// ---------- bucket count (fused totals) -> scans -> scatter ----------------

__global__ __launch_bounds__(BT) void bucket_count(
    const int* __restrict__ dst, int* __restrict__ counts,
    int* __restrict__ totals, int n_edges, int nbuckets, int ept) {
    __shared__ int hist[MAXB];
    for (int i = threadIdx.x; i < nbuckets; i += BT) hist[i] = 0;
    __syncthreads();
    int beg = blockIdx.x * ept;
    int end = min(beg + ept, n_edges);
    for (int e = beg + threadIdx.x; e < end; e += BT)
        atomicAdd(&hist[dst[e] >> 8], 1);
    __syncthreads();
    for (int b = threadIdx.x; b < nbuckets; b += BT) {
        int h = hist[b];
        counts[b * NCHUNK + blockIdx.x] = h;
        if (h) atomicAdd(&totals[b], h);       // fused bucket_totals
    }
}

__global__ __launch_bounds__(MAXB) void scan_small(
    const int* __restrict__ totals, int* __restrict__ bbase, int nbuckets) {
    __shared__ int lds[MAXB];
    int tid = threadIdx.x;
    int v = (tid < nbuckets) ? totals[tid] : 0;
    lds[tid] = v;
    __syncthreads();
    for (int off = 1; off < MAXB; off <<= 1) {
        int t = (tid >= off) ? lds[tid - off] : 0;
        __syncthreads();
        lds[tid] += t;
        __syncthreads();
    }
    if (tid < nbuckets) bbase[tid] = lds[tid] - v;
}

__global__ __launch_bounds__(NPB) void scan_within(
    int* __restrict__ counts, const int* __restrict__ bbase) {
    __shared__ int lds[NPB];
    int b = blockIdx.x, tid = threadIdx.x;
    int v = counts[b * NCHUNK + tid];
    lds[tid] = v;
    __syncthreads();
    for (int off = 1; off < NPB; off <<= 1) {
        int t = (tid >= off) ? lds[tid - off] : 0;
        __syncthreads();
        lds[tid] += t;
        __syncthreads();
    }
    counts[b * NCHUNK + tid] = bbase[b] + lds[tid] - v;
}

__global__ __launch_bounds__(BT) void bucket_scatter(
    const int* __restrict__ src, const int* __restrict__ dst,
    const int* __restrict__ base, unsigned* __restrict__ packed,
    int n_edges, int nbuckets, int ept) {
    __shared__ int cur[MAXB];
    for (int b = threadIdx.x; b < nbuckets; b += BT)
        cur[b] = base[b * NCHUNK + blockIdx.x];
    __syncthreads();
    int beg = blockIdx.x * ept;
    int end = min(beg + ept, n_edges);
    for (int e = beg + threadIdx.x; e < end; e += BT) {
        int s = src[e], d = dst[e];
        int slot = atomicAdd(&cur[d >> 8], 1);
        packed[slot] = (unsigned)s | ((unsigned)(d & 255) << 24);
    }
}

// ---------- per-bucket counting sort -> global CSR (LDS-cached) ------------

__global__ __launch_bounds__(NPB) void csr_build(
    const unsigned* __restrict__ packed, const int* __restrict__ base,
    int* __restrict__ rowptr, int* __restrict__ csr,
    int n_nodes, int nbuckets, int n_edges) {
    __shared__ int cnt[NPB];
    __shared__ int cur[NPB];
    __shared__ unsigned cache[CSR_CAP];
    int b = blockIdx.x, tid = threadIdx.x;
    int pBeg = base[b * NCHUNK];
    int pEnd = (b + 1 < nbuckets) ? base[(b + 1) * NCHUNK] : n_edges;
    int sz = pEnd - pBeg;
    int m = min(sz, CSR_CAP);
    cnt[tid] = 0;
    for (int i = tid; i < m; i += NPB) cache[i] = packed[pBeg + i];
    __syncthreads();
    for (int i = tid; i < sz; i += NPB) {
        unsigned p = (i < m) ? cache[i] : packed[pBeg + i];
        atomicAdd(&cnt[p >> 24], 1);
    }
    __syncthreads();
    int v = cnt[tid];
    cur[tid] = v;
    __syncthreads();
    for (int off = 1; off < NPB; off <<= 1) {
        int t = (tid >= off) ? cur[tid - off] : 0;
        __syncthreads();
        cur[tid] += t;
        __syncthreads();
    }
    int gbase = pBeg + cur[tid] - v;
    int n = (b << 8) + tid;
    if (n < n_nodes) rowptr[n] = gbase;
    if (b == nbuckets - 1 && tid == 0) rowptr[n_nodes] = n_edges;
    cur[tid] = gbase;
    __syncthreads();
    for (int i = tid; i < sz; i += NPB) {
        unsigned p = (i < m) ? cache[i] : packed[pBeg + i];
        int slot = atomicAdd(&cur[p >> 24], 1);
        csr[slot] = (int)(p & 0xFFFFFF);
    }
}

// ---------- gather1 (+fused dense2): 2 lanes/node, 8-deep load pipeline ----

__global__ __launch_bounds__(NT) void gather1_kernel(
    const uint4* __restrict__ xr8v,        // 2 uint4 per node row (32 fp8)
    const float* __restrict__ xroot,
    const int* __restrict__ rowptr, const int* __restrict__ csr,
    const float* __restrict__ W2_rel, const float* __restrict__ b2,
    const float* __restrict__ W2_root,
    __hip_bfloat16* __restrict__ h2, float* __restrict__ hroot, int n_nodes) {
    __shared__ float sWrelT[H_SIZE * 17];  // [j][c] stride 17
    __shared__ float sWrootT[H_SIZE * 17];
    __shared__ float sb[16];
    __shared__ float sh[128][33];          // 128 nodes/block
    int tid = threadIdx.x;
    for (int i = tid; i < H_SIZE * 17; i += NT) { sWrelT[i] = 0.f; sWrootT[i] = 0.f; }
    __syncthreads();
    for (int i = tid; i < N_CLASSES * H_SIZE; i += NT) {
        int c = i >> 5, j = i & 31;
        sWrelT[j * 17 + c] = W2_rel[i];
        sWrootT[j * 17 + c] = W2_root[i];
    }
    if (tid < 16) sb[tid] = (tid < N_CLASSES) ? b2[tid] : 0.f;

    int t = blockIdx.x * NT + tid;
    int n = t >> 1, c1 = t & 1;            // 2 lanes/node; c1 = 16-feat half
    float a[16] = {0.f,0.f,0.f,0.f,0.f,0.f,0.f,0.f,
                   0.f,0.f,0.f,0.f,0.f,0.f,0.f,0.f};
    if (n < n_nodes) {
        int beg = rowptr[n], end = rowptr[n + 1];
        int i = beg;
        for (; i + 8 <= end; i += 8) {     // 8 edges/iter: 8 row loads in flight
            int e0 = csr[i + c1];
            int e1 = csr[i + 2 + c1];
            int e2 = csr[i + 4 + c1];
            int e3 = csr[i + 6 + c1];
            uint4 p0 = xr8v[(size_t)__shfl(e0, 0, 2) * 2 + c1];
            uint4 p1 = xr8v[(size_t)__shfl(e0, 1, 2) * 2 + c1];
            uint4 p2 = xr8v[(size_t)__shfl(e1, 0, 2) * 2 + c1];
            uint4 p3 = xr8v[(size_t)__shfl(e1, 1, 2) * 2 + c1];
            uint4 p4 = xr8v[(size_t)__shfl(e2, 0, 2) * 2 + c1];
            uint4 p5 = xr8v[(size_t)__shfl(e2, 1, 2) * 2 + c1];
            uint4 p6 = xr8v[(size_t)__shfl(e3, 0, 2) * 2 + c1];
            uint4 p7 = xr8v[(size_t)__shfl(e3, 1, 2) * 2 + c1];
            ACC16(p0); ACC16(p1); ACC16(p2); ACC16(p3);
            ACC16(p4); ACC16(p5); ACC16(p6); ACC16(p7);
        }
        if (i + 4 <= end) {
            int e0 = csr[i + c1];
            int e1 = csr[i + 2 + c1];
            uint4 p0 = xr8v[(size_t)__shfl(e0, 0, 2) * 2 + c1];
            uint4 p1 = xr8v[(size_t)__shfl(e0, 1, 2) * 2 + c1];
            uint4 p2 = xr8v[(size_t)__shfl(e1, 0, 2) * 2 + c1];
            uint4 p3 = xr8v[(size_t)__shfl(e1, 1, 2) * 2 + c1];
            ACC16(p0); ACC16(p1); ACC16(p2); ACC16(p3);
            i += 4;
        }
        if (i + 2 <= end) {
            int e0 = csr[i + c1];
            uint4 p0 = xr8v[(size_t)__shfl(e0, 0, 2) * 2 + c1];
            uint4 p1 = xr8v[(size_t)__shfl(e0, 1, 2) * 2 + c1];
            ACC16(p0); ACC16(p1);
            i += 2;
        }
        if (i < end) {                     // single leftover edge (broadcast)
            int e = csr[i];
            uint4 p = xr8v[(size_t)e * 2 + c1];
            ACC16(p);
        }
        const float4* xr4 = reinterpret_cast<const float4*>(
            xroot + (size_t)n * 32 + c1 * 16);
#pragma unroll
        for (int q = 0; q < 4; ++q) {
            float4 v = xr4[q];
            a[q * 4 + 0] = fmaxf(a[q * 4 + 0] + v.x, 0.f);
            a[q * 4 + 1] = fmaxf(a[q * 4 + 1] + v.y, 0.f);
            a[q * 4 + 2] = fmaxf(a[q * 4 + 2] + v.z, 0.f);
            a[q * 4 + 3] = fmaxf(a[q * 4 + 3] + v.w, 0.f);
        }
    }
    int nl = tid >> 1;
#pragma unroll
    for (int j = 0; j < 16; ++j) sh[nl][c1 * 16 + j] = a[j];
    __syncthreads();

    // fused dense2: 128 nodes x 16 cols = 2048 items, 8 passes
#pragma unroll
    for (int pass = 0; pass < 8; ++pass) {
        int idx = pass * NT + tid;
        int nl2 = idx >> 4, c = idx & 15;
        int n2 = blockIdx.x * 128 + nl2;
        if (n2 < n_nodes) {
            float ar = 0.f, ao = 0.f;
#pragma unroll
            for (int j = 0; j < H_SIZE; ++j) {
                float hv = sh[nl2][j];
                ar += hv * sWrelT[j * 17 + c];
                ao += hv * sWrootT[j * 17 + c];
            }
            h2[(size_t)n2 * 16 + c] = __float2bfloat16(ar);
            hroot[(size_t)n2 * 16 + c] = ao + sb[c];
        }
    }
}

// ---------- gather2 + loss: 2 lanes/node, 8-deep load pipeline -------------

__global__ __launch_bounds__(NT) void gather2_loss_kernel(
    const uint4* __restrict__ h2v,         // 2 uint4 per node row (16 bf16)
    const float* __restrict__ hroot,
    const int* __restrict__ rowptr, const int* __restrict__ csr,
    const int* __restrict__ y, float* __restrict__ loss,
    int n_nodes, float invN) {
    int t = blockIdx.x * NT + threadIdx.x;
    int n = t >> 1, c1 = t & 1;            // c1 = 8-class half
    int lane = threadIdx.x & 63;
    bool active = (n < n_nodes);

    float a[8] = {0.f,0.f,0.f,0.f,0.f,0.f,0.f,0.f};
    int yv = 0;
    if (active) {
        int beg = rowptr[n], end = rowptr[n + 1];
        int i = beg;
        for (; i + 8 <= end; i += 8) {     // 8 edges/iter: 8 row loads in flight
            int e0 = csr[i + c1];
            int e1 = csr[i + 2 + c1];
            int e2 = csr[i + 4 + c1];
            int e3 = csr[i + 6 + c1];
            uint4 p0 = h2v[(size_t)__shfl(e0, 0, 2) * 2 + c1];
            uint4 p1 = h2v[(size_t)__shfl(e0, 1, 2) * 2 + c1];
            uint4 p2 = h2v[(size_t)__shfl(e1, 0, 2) * 2 + c1];
            uint4 p3 = h2v[(size_t)__shfl(e1, 1, 2) * 2 + c1];
            uint4 p4 = h2v[(size_t)__shfl(e2, 0, 2) * 2 + c1];
            uint4 p5 = h2v[(size_t)__shfl(e2, 1, 2) * 2 + c1];
            uint4 p6 = h2v[(size_t)__shfl(e3, 0, 2) * 2 + c1];
            uint4 p7 = h2v[(size_t)__shfl(e3, 1, 2) * 2 + c1];
            ACC8(p0); ACC8(p1); ACC8(p2); ACC8(p3);
            ACC8(p4); ACC8(p5); ACC8(p6); ACC8(p7);
        }
        if (i + 4 <= end) {
            int e0 = csr[i + c1];
            int e1 = csr[i + 2 + c1];
            uint4 p0 = h2v[(size_t)__shfl(e0, 0, 2) * 2 + c1];
            uint4 p1 = h2v[(size_t)__shfl(e0, 1, 2) * 2 + c1];
            uint4 p2 = h2v[(size_t)__shfl(e1, 0, 2) * 2 + c1];
            uint4 p3 = h2v[(size_t)__shfl(e1, 1, 2) * 2 + c1];
            ACC8(p0); ACC8(p1); ACC8(p2); ACC8(p3);
            i += 4;
        }
        if (i + 2 <= end) {
            int e0 = csr[i + c1];
            uint4 p0 = h2v[(size_t)__shfl(e0, 0, 2) * 2 + c1];
            uint4 p1 = h2v[(size_t)__shfl(e0, 1, 2) * 2 + c1];
            ACC8(p0); ACC8(p1);
            i += 2;
        }
        if (i < end) {
            int e = csr[i];
            uint4 p = h2v[(size_t)e * 2 + c1];
            ACC8(p);
        }
        const float4* hr4 = reinterpret_cast<const float4*>(
            hroot + (size_t)n * 16 + c1 * 8);
        float4 h0 = hr4[0], h1 = hr4[1];
        a[0] += h0.x; a[1] += h0.y; a[2] += h0.z; a[3] += h0.w;
        a[4] += h1.x; a[5] += h1.y; a[6] += h1.z; a[7] += h1.w;
        yv = y[n];
    }
    // log-softmax: lane c1=0 holds classes 0..7, lane c1=1 holds 8..15 (8,9 valid)
    bool full = active && (c1 == 0);
    float m = -INFINITY;
#pragma unroll
    for (int j = 0; j < 8; ++j) {
        bool v = (j < 2) ? active : full;
        m = fmaxf(m, v ? a[j] : -INFINITY);
    }
    m = fmaxf(m, __shfl_xor(m, 1, 64));
    float es = 0.f;
#pragma unroll
    for (int j = 0; j < 8; ++j) {
        bool v = (j < 2) ? active : full;
        es += v ? expf(a[j] - m) : 0.f;
    }
    es += __shfl_xor(es, 1, 64);
    int yl = yv & 7;
    float lyc = 0.f;
#pragma unroll
    for (int j = 0; j < 8; ++j) lyc = (j == yl) ? a[j] : lyc;
    float ly = __shfl(lyc, (lane & ~1) + (yv >> 3), 64);
    float contrib = (active && c1 == 0) ? (m + logf(es) - ly) * invN : 0.f;

#pragma unroll
    for (int o = 32; o > 0; o >>= 1) contrib += __shfl_down(contrib, o, 64);
    __shared__ float part[NT / 64];
    if (lane == 0) part[threadIdx.x >> 6] = contrib;
    __syncthreads();
    if (threadIdx.x == 0) {
        float v = 0.f;
#pragma unroll
        for (int w = 0; w < NT / 64; ++w) v += part[w];
        atomicAdd(loss, v);
    }
}

// ---------------------------------------------------------------------------

extern "C" void kernel_launch(void* const* d_in, const int* in_sizes, int n_in,
                              void* d_out, int out_size, void* d_ws, size_t ws_size,
                              hipStream_t stream) {
    const float* x       = (const float*)d_in[0];
    const int*   ei      = (const int*)d_in[1];
    const int*   y       = (const int*)d_in[2];
    const float* W1_rel  = (const float*)d_in[3];
    const float* b1_rel  = (const float*)d_in[4];
    const float* W1_root = (const float*)d_in[5];
    const float* W2_rel  = (const float*)d_in[6];
    const float* b2_rel  = (const float*)d_in[7];
    const float* W2_root = (const float*)d_in[8];
    float* loss = (float*)d_out;

    const int n_nodes = in_sizes[0] / D_FEAT;
    const int n_edges = in_sizes[1] / 2;
    const int* src = ei;
    const int* dst = ei + n_edges;

    const int nbuckets = (n_nodes + NPB - 1) / NPB;
    const int M = nbuckets * NCHUNK;
    const int ept = (n_edges + NCHUNK - 1) / NCHUNK;

    size_t off = 0;
    auto alloc = [&](size_t bytes) {
        void* p = (char*)d_ws + off;
        off = (off + bytes + 255) & ~(size_t)255;
        return p;
    };
    int*            counts = (int*)alloc((size_t)(M + 1) * 4);
    int*            totals = (int*)alloc((size_t)MAXB * 4);
    int*            bbase  = (int*)alloc((size_t)MAXB * 4);
    unsigned*       packed = (unsigned*)alloc((size_t)n_edges * 4);
    int*            rowptr = (int*)alloc((size_t)(n_nodes + 1) * 4);
    int*            csr    = (int*)alloc((size_t)n_edges * 4);
    unsigned*       xr8    = (unsigned*)alloc((size_t)n_nodes * 32);      // fp8 [n][32]
    float*          xroot  = (float*)alloc((size_t)n_nodes * H_SIZE * 4);
    __hip_bfloat16* h2     = (__hip_bfloat16*)alloc((size_t)n_nodes * 16 * 2);
    float*          hroot  = (float*)alloc((size_t)n_nodes * 16 * 4);

    // dense pre-transform via MFMA (64 nodes/block)
    dense1_mfma<<<(n_nodes + 63) / 64, NT, 0, stream>>>(
        x, W1_rel, b1_rel, W1_root, xr8, xroot, n_nodes);

    // bucket build -> packed -> CSR
    hipMemsetAsync(totals, 0, (size_t)MAXB * 4, stream);
    bucket_count<<<NCHUNK, BT, 0, stream>>>(dst, counts, totals,
                                            n_edges, nbuckets, ept);
    scan_small<<<1, MAXB, 0, stream>>>(totals, bbase, nbuckets);
    scan_within<<<nbuckets, NPB, 0, stream>>>(counts, bbase);
    bucket_scatter<<<NCHUNK, BT, 0, stream>>>(src, dst, counts, packed,
                                              n_edges, nbuckets, ept);
    csr_build<<<nbuckets, NPB, 0, stream>>>(packed, counts, rowptr, csr,
                                            n_nodes, nbuckets, n_edges);

    // layer 1 aggregate + fused dense2 (128 nodes per block, 2 lanes/node)
    gather1_kernel<<<(n_nodes + 127) / 128, NT, 0, stream>>>(
        (const uint4*)xr8, xroot, rowptr, csr,
        W2_rel, b2_rel, W2_root, h2, hroot, n_nodes);

    // layer 2 aggregate + loss (128 nodes per block, 2 lanes/node)
    hipMemsetAsync(loss, 0, sizeof(float), stream);
    gather2_loss_kernel<<<(n_nodes + 127) / 128, NT, 0, stream>>>(
        (const uint4*)h2, hroot, rowptr, csr, y, loss,
        n_nodes, 1.f / (float)n_nodes);
}

// Round 17
// 155.154 us; speedup vs baseline: 1.3185x; 1.0231x over previous
//
#include <hip/hip_runtime.h>
#include <hip/hip_bf16.h>
#include <hip/hip_fp8.h>

#define D_FEAT 64
#define H_SIZE 32
#define N_CLASSES 10
#define NPB 256          // nodes per bucket (bucket = dst >> 8)
#define MAXB 512
#define NCHUNK 256       // edge chunks for count/scatter passes
#define BT 1024
#define NT 256
#define CSR_CAP 12032    // csr_build LDS cache entries

using short8 = __attribute__((ext_vector_type(8))) short;
using f32x4v = __attribute__((ext_vector_type(4))) float;

__device__ inline short f2bf(float f) {
    __hip_bfloat16 h = __float2bfloat16(f);
    return *reinterpret_cast<short*>(&h);
}

// fp8 byte -> float
#define F8(u, s) ({ __hip_fp8_e4m3 _f; _f.__x = (unsigned char)(((u) >> (s)) & 0xff); (float)_f; })

#define ACC16(p) do { \
    a[0]  += F8((p).x, 0);  a[1]  += F8((p).x, 8);  a[2]  += F8((p).x, 16); a[3]  += F8((p).x, 24); \
    a[4]  += F8((p).y, 0);  a[5]  += F8((p).y, 8);  a[6]  += F8((p).y, 16); a[7]  += F8((p).y, 24); \
    a[8]  += F8((p).z, 0);  a[9]  += F8((p).z, 8);  a[10] += F8((p).z, 16); a[11] += F8((p).z, 24); \
    a[12] += F8((p).w, 0);  a[13] += F8((p).w, 8);  a[14] += F8((p).w, 16); a[15] += F8((p).w, 24); } while (0)

// accumulate 10 fp8 classes from a uint4 into a[0..9]
#define ACC10(p) do { \
    a[0] += F8((p).x, 0);  a[1] += F8((p).x, 8);  a[2] += F8((p).x, 16); a[3] += F8((p).x, 24); \
    a[4] += F8((p).y, 0);  a[5] += F8((p).y, 8);  a[6] += F8((p).y, 16); a[7] += F8((p).y, 24); \
    a[8] += F8((p).z, 0);  a[9] += F8((p).z, 8); } while (0)

// ---------- dense1 via MFMA: O = x @ [W1_rel^T | W1_root^T] ---------------

__global__ __launch_bounds__(NT) void dense1_mfma(
    const float* __restrict__ x, const float* __restrict__ W1_rel,
    const float* __restrict__ b1, const float* __restrict__ W1_root,
    unsigned* __restrict__ xr8, float* __restrict__ xroot, int n_nodes) {
    __shared__ unsigned short sW[64 * 72];   // [outcol n][k] bf16, pad 72
    __shared__ float sOut[64 * 65];          // [node][outcol] f32, pad 65
    __shared__ float sb[H_SIZE];
    int tid = threadIdx.x;
    for (int i = tid; i < 64 * 64; i += NT) {
        int n = i >> 6, k = i & 63;
        float w = (n < 32) ? W1_rel[n * 64 + k] : W1_root[(n - 32) * 64 + k];
        sW[n * 72 + k] = (unsigned short)f2bf(w);
    }
    if (tid < H_SIZE) sb[tid] = b1[tid];
    __syncthreads();

    int lane = tid & 63, wave = tid >> 6;
    int r16 = lane & 15, h = lane >> 4;

    short8 bf[4][2];
#pragma unroll
    for (int t = 0; t < 4; ++t)
#pragma unroll
        for (int s = 0; s < 2; ++s) {
            const unsigned short* p = &sW[(t * 16 + r16) * 72 + s * 32 + h * 8];
            bf[t][s] = *reinterpret_cast<const short8*>(p);
        }

    int nbase = blockIdx.x * 64 + wave * 16;
    int row = nbase + r16;
    int rowc = min(row, n_nodes - 1);

    short8 af[2];
#pragma unroll
    for (int s = 0; s < 2; ++s) {
        const float* px = x + (size_t)rowc * D_FEAT + s * 32 + h * 8;
        float4 lo = *reinterpret_cast<const float4*>(px);
        float4 hi = *reinterpret_cast<const float4*>(px + 4);
        short8 a;
        a[0] = f2bf(lo.x); a[1] = f2bf(lo.y); a[2] = f2bf(lo.z); a[3] = f2bf(lo.w);
        a[4] = f2bf(hi.x); a[5] = f2bf(hi.y); a[6] = f2bf(hi.z); a[7] = f2bf(hi.w);
        af[s] = a;
    }

    f32x4v acc[4] = {{0.f,0.f,0.f,0.f},{0.f,0.f,0.f,0.f},
                     {0.f,0.f,0.f,0.f},{0.f,0.f,0.f,0.f}};
#pragma unroll
    for (int t = 0; t < 4; ++t) {
        acc[t] = __builtin_amdgcn_mfma_f32_16x16x32_bf16(af[0], bf[t][0], acc[t], 0, 0, 0);
        acc[t] = __builtin_amdgcn_mfma_f32_16x16x32_bf16(af[1], bf[t][1], acc[t], 0, 0, 0);
    }
#pragma unroll
    for (int t = 0; t < 4; ++t)
#pragma unroll
        for (int r = 0; r < 4; ++r)
            sOut[(wave * 16 + h * 4 + r) * 65 + t * 16 + r16] = acc[t][r];
    __syncthreads();

    int nl = lane;
    int g = blockIdx.x * 64 + nl;
    if (g < n_nodes) {
        if (wave < 2) {
            unsigned w4[4];
#pragma unroll
            for (int q = 0; q < 4; ++q) {
                unsigned wd = 0;
#pragma unroll
                for (int b = 0; b < 4; ++b) {
                    float v = sOut[nl * 65 + wave * 16 + q * 4 + b];
                    __hip_fp8_e4m3 f8(v);
                    wd |= ((unsigned)f8.__x) << (8 * b);
                }
                w4[q] = wd;
            }
            *reinterpret_cast<uint4*>(&xr8[(size_t)g * 8 + wave * 4]) =
                make_uint4(w4[0], w4[1], w4[2], w4[3]);
        } else {
            int co = (wave - 2) * 16;
#pragma unroll
            for (int q = 0; q < 4; ++q) {
                float4 v;
                v.x = sOut[nl * 65 + 32 + co + q * 4 + 0] + sb[co + q * 4 + 0];
                v.y = sOut[nl * 65 + 32 + co + q * 4 + 1] + sb[co + q * 4 + 1];
                v.z = sOut[nl * 65 + 32 + co + q * 4 + 2] + sb[co + q * 4 + 2];
                v.w = sOut[nl * 65 + 32 + co + q * 4 + 3] + sb[co + q * 4 + 3];
                *reinterpret_cast<float4*>(&xroot[(size_t)g * 32 + co + q * 4]) = v;
            }
        }
    }
}

// ---------- bucket count (fused totals) -> scans -> scatter ----------------

__global__ __launch_bounds__(BT) void bucket_count(
    const int* __restrict__ dst, int* __restrict__ counts,
    int* __restrict__ totals, int n_edges, int nbuckets, int ept) {
    __shared__ int hist[MAXB];
    for (int i = threadIdx.x; i < nbuckets; i += BT) hist[i] = 0;
    __syncthreads();
    int beg = blockIdx.x * ept;
    int end = min(beg + ept, n_edges);
    for (int e = beg + threadIdx.x; e < end; e += BT)
        atomicAdd(&hist[dst[e] >> 8], 1);
    __syncthreads();
    for (int b = threadIdx.x; b < nbuckets; b += BT) {
        int h = hist[b];
        counts[b * NCHUNK + blockIdx.x] = h;
        if (h) atomicAdd(&totals[b], h);       // fused bucket_totals
    }
}

__global__ __launch_bounds__(MAXB) void scan_small(
    const int* __restrict__ totals, int* __restrict__ bbase, int nbuckets) {
    __shared__ int lds[MAXB];
    int tid = threadIdx.x;
    int v = (tid < nbuckets) ? totals[tid] : 0;
    lds[tid] = v;
    __syncthreads();
    for (int off = 1; off < MAXB; off <<= 1) {
        int t = (tid >= off) ? lds[tid - off] : 0;
        __syncthreads();
        lds[tid] += t;
        __syncthreads();
    }
    if (tid < nbuckets) bbase[tid] = lds[tid] - v;
}

__global__ __launch_bounds__(NPB) void scan_within(
    int* __restrict__ counts, const int* __restrict__ bbase) {
    __shared__ int lds[NPB];
    int b = blockIdx.x, tid = threadIdx.x;
    int v = counts[b * NCHUNK + tid];
    lds[tid] = v;
    __syncthreads();
    for (int off = 1; off < NPB; off <<= 1) {
        int t = (tid >= off) ? lds[tid - off] : 0;
        __syncthreads();
        lds[tid] += t;
        __syncthreads();
    }
    counts[b * NCHUNK + tid] = bbase[b] + lds[tid] - v;
}

__global__ __launch_bounds__(BT) void bucket_scatter(
    const int* __restrict__ src, const int* __restrict__ dst,
    const int* __restrict__ base, unsigned* __restrict__ packed,
    int n_edges, int nbuckets, int ept) {
    __shared__ int cur[MAXB];
    for (int b = threadIdx.x; b < nbuckets; b += BT)
        cur[b] = base[b * NCHUNK + blockIdx.x];
    __syncthreads();
    int beg = blockIdx.x * ept;
    int end = min(beg + ept, n_edges);
    for (int e = beg + threadIdx.x; e < end; e += BT) {
        int s = src[e], d = dst[e];
        int slot = atomicAdd(&cur[d >> 8], 1);
        packed[slot] = (unsigned)s | ((unsigned)(d & 255) << 24);
    }
}

// ---------- per-bucket counting sort -> global CSR (LDS-cached) ------------

__global__ __launch_bounds__(NPB) void csr_build(
    const unsigned* __restrict__ packed, const int* __restrict__ base,
    int* __restrict__ rowptr, int* __restrict__ csr,
    int n_nodes, int nbuckets, int n_edges) {
    __shared__ int cnt[NPB];
    __shared__ int cur[NPB];
    __shared__ unsigned cache[CSR_CAP];
    int b = blockIdx.x, tid = threadIdx.x;
    int pBeg = base[b * NCHUNK];
    int pEnd = (b + 1 < nbuckets) ? base[(b + 1) * NCHUNK] : n_edges;
    int sz = pEnd - pBeg;
    int m = min(sz, CSR_CAP);
    cnt[tid] = 0;
    for (int i = tid; i < m; i += NPB) cache[i] = packed[pBeg + i];
    __syncthreads();
    for (int i = tid; i < sz; i += NPB) {
        unsigned p = (i < m) ? cache[i] : packed[pBeg + i];
        atomicAdd(&cnt[p >> 24], 1);
    }
    __syncthreads();
    int v = cnt[tid];
    cur[tid] = v;
    __syncthreads();
    for (int off = 1; off < NPB; off <<= 1) {
        int t = (tid >= off) ? cur[tid - off] : 0;
        __syncthreads();
        cur[tid] += t;
        __syncthreads();
    }
    int gbase = pBeg + cur[tid] - v;
    int n = (b << 8) + tid;
    if (n < n_nodes) rowptr[n] = gbase;
    if (b == nbuckets - 1 && tid == 0) rowptr[n_nodes] = n_edges;
    cur[tid] = gbase;
    __syncthreads();
    for (int i = tid; i < sz; i += NPB) {
        unsigned p = (i < m) ? cache[i] : packed[pBeg + i];
        int slot = atomicAdd(&cur[p >> 24], 1);
        csr[slot] = (int)(p & 0xFFFFFF);
    }
}

// ---------- gather1 (+fused dense2, fp8 h2 out): 2 lanes/node, 8-deep ------

__global__ __launch_bounds__(NT) void gather1_kernel(
    const uint4* __restrict__ xr8v,        // 2 uint4 per node row (32 fp8)
    const float* __restrict__ xroot,
    const int* __restrict__ rowptr, const int* __restrict__ csr,
    const float* __restrict__ W2_rel, const float* __restrict__ b2,
    const float* __restrict__ W2_root,
    unsigned* __restrict__ h2b, float* __restrict__ hroot, int n_nodes) {
    __shared__ float sWrelT[H_SIZE * 17];  // [j][c] stride 17
    __shared__ float sWrootT[H_SIZE * 17];
    __shared__ float sb[16];
    __shared__ float sh[128][33];          // 128 nodes/block
    int tid = threadIdx.x;
    for (int i = tid; i < H_SIZE * 17; i += NT) { sWrelT[i] = 0.f; sWrootT[i] = 0.f; }
    __syncthreads();
    for (int i = tid; i < N_CLASSES * H_SIZE; i += NT) {
        int c = i >> 5, j = i & 31;
        sWrelT[j * 17 + c] = W2_rel[i];
        sWrootT[j * 17 + c] = W2_root[i];
    }
    if (tid < 16) sb[tid] = (tid < N_CLASSES) ? b2[tid] : 0.f;

    int t = blockIdx.x * NT + tid;
    int n = t >> 1, c1 = t & 1;            // 2 lanes/node; c1 = 16-feat half
    float a[16] = {0.f,0.f,0.f,0.f,0.f,0.f,0.f,0.f,
                   0.f,0.f,0.f,0.f,0.f,0.f,0.f,0.f};
    if (n < n_nodes) {
        int beg = rowptr[n], end = rowptr[n + 1];
        int i = beg;
        for (; i + 8 <= end; i += 8) {     // 8 edges/iter: 8 row loads in flight
            int e0 = csr[i + c1];
            int e1 = csr[i + 2 + c1];
            int e2 = csr[i + 4 + c1];
            int e3 = csr[i + 6 + c1];
            uint4 p0 = xr8v[(size_t)__shfl(e0, 0, 2) * 2 + c1];
            uint4 p1 = xr8v[(size_t)__shfl(e0, 1, 2) * 2 + c1];
            uint4 p2 = xr8v[(size_t)__shfl(e1, 0, 2) * 2 + c1];
            uint4 p3 = xr8v[(size_t)__shfl(e1, 1, 2) * 2 + c1];
            uint4 p4 = xr8v[(size_t)__shfl(e2, 0, 2) * 2 + c1];
            uint4 p5 = xr8v[(size_t)__shfl(e2, 1, 2) * 2 + c1];
            uint4 p6 = xr8v[(size_t)__shfl(e3, 0, 2) * 2 + c1];
            uint4 p7 = xr8v[(size_t)__shfl(e3, 1, 2) * 2 + c1];
            ACC16(p0); ACC16(p1); ACC16(p2); ACC16(p3);
            ACC16(p4); ACC16(p5); ACC16(p6); ACC16(p7);
        }
        if (i + 4 <= end) {
            int e0 = csr[i + c1];
            int e1 = csr[i + 2 + c1];
            uint4 p0 = xr8v[(size_t)__shfl(e0, 0, 2) * 2 + c1];
            uint4 p1 = xr8v[(size_t)__shfl(e0, 1, 2) * 2 + c1];
            uint4 p2 = xr8v[(size_t)__shfl(e1, 0, 2) * 2 + c1];
            uint4 p3 = xr8v[(size_t)__shfl(e1, 1, 2) * 2 + c1];
            ACC16(p0); ACC16(p1); ACC16(p2); ACC16(p3);
            i += 4;
        }
        if (i + 2 <= end) {
            int e0 = csr[i + c1];
            uint4 p0 = xr8v[(size_t)__shfl(e0, 0, 2) * 2 + c1];
            uint4 p1 = xr8v[(size_t)__shfl(e0, 1, 2) * 2 + c1];
            ACC16(p0); ACC16(p1);
            i += 2;
        }
        if (i < end) {                     // single leftover edge (broadcast)
            int e = csr[i];
            uint4 p = xr8v[(size_t)e * 2 + c1];
            ACC16(p);
        }
        const float4* xr4 = reinterpret_cast<const float4*>(
            xroot + (size_t)n * 32 + c1 * 16);
#pragma unroll
        for (int q = 0; q < 4; ++q) {
            float4 v = xr4[q];
            a[q * 4 + 0] = fmaxf(a[q * 4 + 0] + v.x, 0.f);
            a[q * 4 + 1] = fmaxf(a[q * 4 + 1] + v.y, 0.f);
            a[q * 4 + 2] = fmaxf(a[q * 4 + 2] + v.z, 0.f);
            a[q * 4 + 3] = fmaxf(a[q * 4 + 3] + v.w, 0.f);
        }
    }
    int nl = tid >> 1;
#pragma unroll
    for (int j = 0; j < 16; ++j) sh[nl][c1 * 16 + j] = a[j];
    __syncthreads();

    // fused dense2: 128 nodes x 16 cols, h2 packed to fp8 (uint per 4 classes)
#pragma unroll
    for (int pass = 0; pass < 8; ++pass) {
        int idx = pass * NT + tid;
        int nl2 = idx >> 4, c = idx & 15;
        int n2 = blockIdx.x * 128 + nl2;
        bool valid = (n2 < n_nodes);
        float ar = 0.f, ao = 0.f;
#pragma unroll
        for (int j = 0; j < H_SIZE; ++j) {
            float hv = sh[nl2][j];
            ar += hv * sWrelT[j * 17 + c];
            ao += hv * sWrootT[j * 17 + c];
        }
        // pack 4 classes into one dword via lane shuffles (16-groups intra-wave)
        float r1 = __shfl_down(ar, 1, 64);
        float r2 = __shfl_down(ar, 2, 64);
        float r3 = __shfl_down(ar, 3, 64);
        if (valid) {
            if ((c & 3) == 0) {
                __hip_fp8_e4m3 f0(ar), f1(r1), f2(r2), f3(r3);
                unsigned wd = (unsigned)f0.__x | ((unsigned)f1.__x << 8) |
                              ((unsigned)f2.__x << 16) | ((unsigned)f3.__x << 24);
                h2b[(size_t)n2 * 4 + (c >> 2)] = wd;
            }
            hroot[(size_t)n2 * 16 + c] = ao + sb[c];
        }
    }
}

// ---------- gather2 + loss: edge-parallel lane pairs, fp8 16B rows ---------

__global__ __launch_bounds__(NT) void gather2_loss_kernel(
    const uint4* __restrict__ h2q,         // 1 uint4 per node (16 fp8, 10 valid)
    const float* __restrict__ hroot,
    const int* __restrict__ rowptr, const int* __restrict__ csr,
    const int* __restrict__ y, float* __restrict__ loss,
    int n_nodes, float invN) {
    int t = blockIdx.x * NT + threadIdx.x;
    int n = t >> 1, c1 = t & 1;            // lane pair: c1 = edge-parity
    int lane = threadIdx.x & 63;
    bool active = (n < n_nodes);

    float a[10] = {0.f,0.f,0.f,0.f,0.f,0.f,0.f,0.f,0.f,0.f};
    if (active) {
        int beg = rowptr[n], end = rowptr[n + 1];
        int i = beg;
        for (; i + 8 <= end; i += 8) {     // each lane: 4 edges, 4 rows in flight
            int e0 = csr[i + c1];
            int e1 = csr[i + 2 + c1];
            int e2 = csr[i + 4 + c1];
            int e3 = csr[i + 6 + c1];
            uint4 p0 = h2q[e0];
            uint4 p1 = h2q[e1];
            uint4 p2 = h2q[e2];
            uint4 p3 = h2q[e3];
            ACC10(p0); ACC10(p1); ACC10(p2); ACC10(p3);
        }
        for (; i + 2 <= end; i += 2) {
            int e0 = csr[i + c1];
            uint4 p0 = h2q[e0];
            ACC10(p0);
        }
        if (i < end && c1 == 0) {          // odd leftover edge on lane 0
            uint4 p = h2q[csr[i]];
            ACC10(p);
        }
    }
    // pair combine: both lanes end with full 10-class sums
#pragma unroll
    for (int j = 0; j < N_CLASSES; ++j) a[j] += __shfl_xor(a[j], 1, 64);

    float contrib = 0.f;
    if (active && c1 == 0) {
        const float* hr = hroot + (size_t)n * 16;
        float4 h0 = *reinterpret_cast<const float4*>(hr);
        float4 h1 = *reinterpret_cast<const float4*>(hr + 4);
        float2 hx = *reinterpret_cast<const float2*>(hr + 8);
        a[0] += h0.x; a[1] += h0.y; a[2] += h0.z; a[3] += h0.w;
        a[4] += h1.x; a[5] += h1.y; a[6] += h1.z; a[7] += h1.w;
        a[8] += hx.x; a[9] += hx.y;
        int yv = y[n];
        float m = a[0];
#pragma unroll
        for (int j = 1; j < N_CLASSES; ++j) m = fmaxf(m, a[j]);
        float es = 0.f;
#pragma unroll
        for (int j = 0; j < N_CLASSES; ++j) es += expf(a[j] - m);
        float ly = a[0];
#pragma unroll
        for (int j = 1; j < N_CLASSES; ++j) ly = (j == yv) ? a[j] : ly;
        contrib = (m + logf(es) - ly) * invN;
    }

#pragma unroll
    for (int o = 32; o > 0; o >>= 1) contrib += __shfl_down(contrib, o, 64);
    __shared__ float part[NT / 64];
    if (lane == 0) part[threadIdx.x >> 6] = contrib;
    __syncthreads();
    if (threadIdx.x == 0) {
        float v = 0.f;
#pragma unroll
        for (int w = 0; w < NT / 64; ++w) v += part[w];
        atomicAdd(loss, v);
    }
}

// ---------------------------------------------------------------------------

extern "C" void kernel_launch(void* const* d_in, const int* in_sizes, int n_in,
                              void* d_out, int out_size, void* d_ws, size_t ws_size,
                              hipStream_t stream) {
    const float* x       = (const float*)d_in[0];
    const int*   ei      = (const int*)d_in[1];
    const int*   y       = (const int*)d_in[2];
    const float* W1_rel  = (const float*)d_in[3];
    const float* b1_rel  = (const float*)d_in[4];
    const float* W1_root = (const float*)d_in[5];
    const float* W2_rel  = (const float*)d_in[6];
    const float* b2_rel  = (const float*)d_in[7];
    const float* W2_root = (const float*)d_in[8];
    float* loss = (float*)d_out;

    const int n_nodes = in_sizes[0] / D_FEAT;
    const int n_edges = in_sizes[1] / 2;
    const int* src = ei;
    const int* dst = ei + n_edges;

    const int nbuckets = (n_nodes + NPB - 1) / NPB;
    const int M = nbuckets * NCHUNK;
    const int ept = (n_edges + NCHUNK - 1) / NCHUNK;

    size_t off = 0;
    auto alloc = [&](size_t bytes) {
        void* p = (char*)d_ws + off;
        off = (off + bytes + 255) & ~(size_t)255;
        return p;
    };
    int*      counts = (int*)alloc((size_t)(M + 1) * 4);
    int*      totals = (int*)alloc((size_t)MAXB * 4);
    int*      bbase  = (int*)alloc((size_t)MAXB * 4);
    unsigned* packed = (unsigned*)alloc((size_t)n_edges * 4);
    int*      rowptr = (int*)alloc((size_t)(n_nodes + 1) * 4);
    int*      csr    = (int*)alloc((size_t)n_edges * 4);
    unsigned* xr8    = (unsigned*)alloc((size_t)n_nodes * 32);   // fp8 [n][32]
    float*    xroot  = (float*)alloc((size_t)n_nodes * H_SIZE * 4);
    unsigned* h2b    = (unsigned*)alloc((size_t)n_nodes * 16);   // fp8 [n][16]
    float*    hroot  = (float*)alloc((size_t)n_nodes * 16 * 4);

    // dense pre-transform via MFMA (64 nodes/block)
    dense1_mfma<<<(n_nodes + 63) / 64, NT, 0, stream>>>(
        x, W1_rel, b1_rel, W1_root, xr8, xroot, n_nodes);

    // bucket build -> packed -> CSR
    hipMemsetAsync(totals, 0, (size_t)MAXB * 4, stream);
    bucket_count<<<NCHUNK, BT, 0, stream>>>(dst, counts, totals,
                                            n_edges, nbuckets, ept);
    scan_small<<<1, MAXB, 0, stream>>>(totals, bbase, nbuckets);
    scan_within<<<nbuckets, NPB, 0, stream>>>(counts, bbase);
    bucket_scatter<<<NCHUNK, BT, 0, stream>>>(src, dst, counts, packed,
                                              n_edges, nbuckets, ept);
    csr_build<<<nbuckets, NPB, 0, stream>>>(packed, counts, rowptr, csr,
                                            n_nodes, nbuckets, n_edges);

    // layer 1 aggregate + fused dense2 (128 nodes per block, 2 lanes/node)
    gather1_kernel<<<(n_nodes + 127) / 128, NT, 0, stream>>>(
        (const uint4*)xr8, xroot, rowptr, csr,
        W2_rel, b2_rel, W2_root, h2b, hroot, n_nodes);

    // layer 2 aggregate + loss (128 nodes per block, edge-parallel pairs)
    hipMemsetAsync(loss, 0, sizeof(float), stream);
    gather2_loss_kernel<<<(n_nodes + 127) / 128, NT, 0, stream>>>(
        (const uint4*)h2b, hroot, rowptr, csr, y, loss,
        n_nodes, 1.f / (float)n_nodes);
}